// Round 12
// baseline (754.566 us; speedup 1.0000x reference)
//
#include <hip/hip_runtime.h>
#include <hip/hip_bf16.h>
#include <math.h>

typedef unsigned short u16;
typedef __attribute__((ext_vector_type(8))) unsigned short u16x8;
typedef __attribute__((ext_vector_type(8))) short bf16x8;
typedef __attribute__((ext_vector_type(4))) float f32x4;

#define BATCH 16
#define NTOK  3136
#define CHN   512
#define NH    8
#define HD    64
#define HHW   56
#define NAG   144
#define PS    12

#define S1PP   72      // stage-1 P-tile pitch (u16)
#define S2PP   152     // stage-2 P-tile pitch (u16)
#define AVP    144     // stage-2 avt LDS pitch (linear)

__device__ __forceinline__ float b2f(u16 u) {
    unsigned int x = ((unsigned int)u) << 16;
    float f;
    __builtin_memcpy(&f, &x, 4);
    return f;
}
__device__ __forceinline__ u16 f2b(float f) {
    unsigned int x;
    __builtin_memcpy(&x, &f, 4);
    unsigned int lsb = (x >> 16) & 1u;
    x += 0x7fffu + lsb;            // round-to-nearest-even (finite values)
    return (u16)(x >> 16);
}
__device__ __forceinline__ void store1(float* p, float v) { *p = v; }
__device__ __forceinline__ void store1(u16* p, float v)   { *p = f2b(v); }

// ---------------------------------------------------------------------------
// fp32 -> bf16 conversion (vectorized, memory-bound)
// ---------------------------------------------------------------------------
__global__ __launch_bounds__(256) void cvt_f32_bf16_kernel(
    const float* __restrict__ src, u16* __restrict__ dst, int n4)
{
    const int idx = blockIdx.x * 256 + threadIdx.x;
    if (idx >= n4) return;
    float4 v = reinterpret_cast<const float4*>(src)[idx];
    ushort4 o;
    o.x = f2b(v.x); o.y = f2b(v.y); o.z = f2b(v.z); o.w = f2b(v.w);
    reinterpret_cast<ushort4*>(dst)[idx] = o;
}

// ---------------------------------------------------------------------------
// MFMA GEMM (m97 pattern): out[m,n] = A[m,:].W[n,:] (+bias), K=512, N=512.
// ---------------------------------------------------------------------------
template <typename OT, bool BIAS>
__global__ __launch_bounds__(256) void mfma_gemm_kernel(
    const u16* __restrict__ A, const u16* __restrict__ W,
    const float* __restrict__ bias, OT* __restrict__ out)
{
    __shared__ u16 Asm[128 * 64];
    __shared__ u16 Bsm[128 * 64];

    const int tid  = threadIdx.x;
    const int lane = tid & 63;
    const int w    = tid >> 6;          // wave 0..3
    const int m0   = blockIdx.x * 128;
    const int n0   = blockIdx.y * 128;
    const int wm   = (w & 1) * 64;      // wave row offset in tile
    const int wn   = (w >> 1) * 64;     // wave col offset in tile

    const int srow = lane >> 3;         // staging row within 8-row chunk
    const int scol = (lane & 7) * 8;    // staging k-offset (elems)

    f32x4 acc[4][4] = {};

    for (int kt = 0; kt < 8; ++kt) {
        const int k0 = kt * 64;
        __syncthreads();                 // LDS free (prev iter's reads done)
        #pragma unroll
        for (int i = 0; i < 4; ++i) {
            const int rb = w * 8 + i * 32;
            __builtin_amdgcn_global_load_lds(
                (const __attribute__((address_space(1))) void*)
                    (A + (size_t)(m0 + rb + srow) * 512 + k0 + scol),
                (__attribute__((address_space(3))) void*)(Asm + rb * 64),
                16, 0, 0);
        }
        #pragma unroll
        for (int i = 0; i < 4; ++i) {
            const int rb = w * 8 + i * 32;
            __builtin_amdgcn_global_load_lds(
                (const __attribute__((address_space(1))) void*)
                    (W + (size_t)(n0 + rb + srow) * 512 + k0 + scol),
                (__attribute__((address_space(3))) void*)(Bsm + rb * 64),
                16, 0, 0);
        }
        __syncthreads();                 // staging complete

        #pragma unroll
        for (int kh = 0; kh < 2; ++kh) {
            bf16x8 af[4], bfr[4];
            #pragma unroll
            for (int t = 0; t < 4; ++t)
                af[t] = *reinterpret_cast<const bf16x8*>(
                    &Asm[(wm + t * 16 + (lane & 15)) * 64 + kh * 32 + (lane >> 4) * 8]);
            #pragma unroll
            for (int t = 0; t < 4; ++t)
                bfr[t] = *reinterpret_cast<const bf16x8*>(
                    &Bsm[(wn + t * 16 + (lane & 15)) * 64 + kh * 32 + (lane >> 4) * 8]);
            #pragma unroll
            for (int i = 0; i < 4; ++i)
                #pragma unroll
                for (int j = 0; j < 4; ++j)
                    acc[i][j] = __builtin_amdgcn_mfma_f32_16x16x32_bf16(
                        af[i], bfr[j], acc[i][j], 0, 0, 0);
        }
    }

    // epilogue: C/D layout col=lane&15, row=(lane>>4)*4+reg  [m89/m91]
    const int quad = lane >> 4;
    const int col  = lane & 15;
    #pragma unroll
    for (int j = 0; j < 4; ++j) {
        const int n = n0 + wn + j * 16 + col;
        const float bv = BIAS ? bias[n] : 0.f;
        #pragma unroll
        for (int i = 0; i < 4; ++i) {
            #pragma unroll
            for (int r = 0; r < 4; ++r) {
                const int m = m0 + wm + i * 16 + quad * 4 + r;
                store1(&out[(size_t)m * 512 + n], acc[i][j][r] + bv);
            }
        }
    }
}

// ---------------------------------------------------------------------------
// Adaptive avg-pool x (b,56,56,c) fp32 -> x_pool (b,144,c) bf16.
// ---------------------------------------------------------------------------
__global__ __launch_bounds__(256) void pool_x_kernel(
    const float* __restrict__ x, u16* __restrict__ x_pool)
{
    const int b = blockIdx.x, pq = blockIdx.y;
    const int p = pq / PS, qq = pq % PS;
    const int sp_ = (p * HHW) / PS, ep_ = ((p + 1) * HHW + PS - 1) / PS;
    const int sq_ = (qq * HHW) / PS, eq_ = ((qq + 1) * HHW + PS - 1) / PS;
    const float inv = 1.0f / (float)((ep_ - sp_) * (eq_ - sq_));
    for (int ch = threadIdx.x; ch < CHN; ch += 256) {
        float acc = 0.f;
        for (int y = sp_; y < ep_; ++y)
            for (int xx = sq_; xx < eq_; ++xx)
                acc += x[((size_t)b * NTOK + y * HHW + xx) * CHN + ch];
        x_pool[((size_t)b * NAG + pq) * CHN + ch] = f2b(acc * inv);
    }
}

// ---------------------------------------------------------------------------
// v (b,tok,512) bf16 -> vt (b,512,tok) bf16.  64x64 LDS tiles, skewed pitch.
// ---------------------------------------------------------------------------
__global__ __launch_bounds__(256) void transpose_v_kernel(
    const u16* __restrict__ v, u16* __restrict__ vt)
{
    __shared__ u16 T[64 * S1PP + 32];
    const int t0 = blockIdx.x * 64;      // token tile
    const int c0 = blockIdx.y * 64;      // channel tile
    const int b  = blockIdx.z;

    const int r  = threadIdx.x >> 2;           // token row 0..63
    const int cc = (threadIdx.x & 3) * 16;     // channel offset {0,16,32,48}
    const u16* src = v + ((size_t)b * NTOK + t0 + r) * CHN + c0 + cc;
    u16x8 a0 = *reinterpret_cast<const u16x8*>(src);
    u16x8 a1 = *reinterpret_cast<const u16x8*>(src + 8);
    const int skw = (cc >> 4) * 8;             // bank skew, keeps 16B alignment
    #pragma unroll
    for (int j = 0; j < 8; ++j) T[(cc + j) * S1PP + r + skw] = a0[j];
    #pragma unroll
    for (int j = 0; j < 8; ++j) T[(cc + 8 + j) * S1PP + r + skw] = a1[j];
    __syncthreads();

    const int cr  = threadIdx.x >> 2;          // channel row 0..63
    const int tt  = (threadIdx.x & 3) * 16;    // token offset
    const int rsk = (cr >> 4) * 8;
    u16* dst = vt + ((size_t)b * CHN + c0 + cr) * NTOK + t0 + tt;
    *reinterpret_cast<u16x8*>(dst)     = *reinterpret_cast<const u16x8*>(&T[cr * S1PP + tt + rsk]);
    *reinterpret_cast<u16x8*>(dst + 8) = *reinterpret_cast<const u16x8*>(&T[cr * S1PP + tt + 8 + rsk]);
}

// ---------------------------------------------------------------------------
// Stage-1 flash attention, MFMA version (unchanged).
// ---------------------------------------------------------------------------
__global__ __launch_bounds__(64) void stage1_mfma_kernel(
    const u16* __restrict__ k, const u16* __restrict__ vt,
    const u16* __restrict__ agent, u16* __restrict__ avt)
{
    __shared__ u16 Pl[16 * S1PP];

    const int lb   = blockIdx.x;
    const int work = (lb & 7) * 144 + (lb >> 3);  // bijective XCD swizzle (1152%8==0)
    const int at   = work % 9;                    // agent tile 0..8
    const int r2   = work / 9;
    const int h    = r2 & 7;
    const int b    = r2 >> 3;

    const int lane = threadIdx.x;
    const int c = lane & 15, g = lane >> 4;

    const u16* kp = k  + (size_t)b * NTOK * CHN + h * HD;
    const u16* vp = vt + ((size_t)(b * NH + h)) * HD * NTOK;
    const u16* ap = agent + ((size_t)b * NAG + at * 16 + c) * CHN + h * HD + g * 8;

    // A (agent) fragments resident in registers: rows=agents, k=d
    bf16x8 af0 = *reinterpret_cast<const bf16x8*>(ap);
    bf16x8 af1 = *reinterpret_cast<const bf16x8*>(ap + 32);

    f32x4 accO[4] = {};                 // O^T, d-tiles 0..3
    float m_ = -1e30f, l_ = 0.f;

    // prologue: K fragments for tile 0 (rows=keys, k=d)
    bf16x8 kf[8];
    #pragma unroll
    for (int kt = 0; kt < 4; ++kt)
        #pragma unroll
        for (int ks = 0; ks < 2; ++ks)
            kf[kt * 2 + ks] = *reinterpret_cast<const bf16x8*>(
                kp + (size_t)(kt * 16 + c) * CHN + ks * 32 + g * 8);

    for (int key0 = 0; key0 < NTOK; key0 += 64) {
        // issue current-tile Vt frags (rows=d, k=keys) + next-tile K frags
        bf16x8 vf[8];
        #pragma unroll
        for (int dt = 0; dt < 4; ++dt)
            #pragma unroll
            for (int kk = 0; kk < 2; ++kk)
                vf[dt * 2 + kk] = *reinterpret_cast<const bf16x8*>(
                    vp + (size_t)(dt * 16 + c) * NTOK + key0 + kk * 32 + g * 8);
        bf16x8 kn[8];
        const bool more = (key0 + 64) < NTOK;
        if (more) {
            #pragma unroll
            for (int kt = 0; kt < 4; ++kt)
                #pragma unroll
                for (int ks = 0; ks < 2; ++ks)
                    kn[kt * 2 + ks] = *reinterpret_cast<const bf16x8*>(
                        kp + (size_t)(key0 + 64 + kt * 16 + c) * CHN + ks * 32 + g * 8);
        }

        // S^T tiles: D[key][agent]
        f32x4 s[4] = {};
        #pragma unroll
        for (int kt = 0; kt < 4; ++kt) {
            s[kt] = __builtin_amdgcn_mfma_f32_16x16x32_bf16(kf[kt * 2 + 0], af0, s[kt], 0, 0, 0);
            s[kt] = __builtin_amdgcn_mfma_f32_16x16x32_bf16(kf[kt * 2 + 1], af1, s[kt], 0, 0, 0);
        }

        // online softmax: keys are in-lane (16 vals) + across g groups (xor 16,32)
        float tmax = -1e30f;
        #pragma unroll
        for (int kt = 0; kt < 4; ++kt)
            #pragma unroll
            for (int r = 0; r < 4; ++r) tmax = fmaxf(tmax, s[kt][r]);
        tmax = fmaxf(tmax, __shfl_xor(tmax, 16));
        tmax = fmaxf(tmax, __shfl_xor(tmax, 32));

        const float mnew  = fmaxf(m_, tmax * 0.125f);   // scale=1/8 folded here
        const float alpha = __expf(m_ - mnew);
        float psum = 0.f;
        #pragma unroll
        for (int kt = 0; kt < 4; ++kt) {
            float p0 = __expf(s[kt][0] * 0.125f - mnew);
            float p1 = __expf(s[kt][1] * 0.125f - mnew);
            float p2 = __expf(s[kt][2] * 0.125f - mnew);
            float p3 = __expf(s[kt][3] * 0.125f - mnew);
            psum += (p0 + p1) + (p2 + p3);
            ushort4 pk;
            pk.x = f2b(p0); pk.y = f2b(p1); pk.z = f2b(p2); pk.w = f2b(p3);
            // P[agent=c][key=kt*16+g*4 .. +3]
            *reinterpret_cast<ushort4*>(&Pl[c * S1PP + kt * 16 + g * 4]) = pk;
        }
        psum += __shfl_xor(psum, 16);
        psum += __shfl_xor(psum, 32);
        l_ = l_ * alpha + psum;
        m_ = mnew;
        #pragma unroll
        for (int dt = 0; dt < 4; ++dt) {
            accO[dt][0] *= alpha; accO[dt][1] *= alpha;
            accO[dt][2] *= alpha; accO[dt][3] *= alpha;
        }

        // cross-lane LDS write->read within the wave: force ordering
        asm volatile("s_waitcnt lgkmcnt(0)" ::: "memory");
        __builtin_amdgcn_sched_barrier(0);

        bf16x8 pf0 = *reinterpret_cast<const bf16x8*>(&Pl[c * S1PP + g * 8]);
        bf16x8 pf1 = *reinterpret_cast<const bf16x8*>(&Pl[c * S1PP + 32 + g * 8]);

        #pragma unroll
        for (int dt = 0; dt < 4; ++dt) {
            accO[dt] = __builtin_amdgcn_mfma_f32_16x16x32_bf16(vf[dt * 2 + 0], pf0, accO[dt], 0, 0, 0);
            accO[dt] = __builtin_amdgcn_mfma_f32_16x16x32_bf16(vf[dt * 2 + 1], pf1, accO[dt], 0, 0, 0);
        }

        if (more) {
            #pragma unroll
            for (int i = 0; i < 8; ++i) kf[i] = kn[i];
        }
    }

    // epilogue: lane holds O^T[d=dt*16+g*4+r][agent=at*16+c] -> write avt
    const float invl = 1.f / l_;
    const size_t dbase = (size_t)(b * NH + h) * HD;
    #pragma unroll
    for (int dt = 0; dt < 4; ++dt)
        #pragma unroll
        for (int r = 0; r < 4; ++r)
            avt[(dbase + dt * 16 + g * 4 + r) * NAG + at * 16 + c] =
                f2b(accO[dt][r] * invl);
}

// ---------------------------------------------------------------------------
// Stage-2 attention, MFMA, fused depthwise conv.
// Order: issue AVs/dwW staging -> QK^T (global A-frags) -> __syncthreads
// (staging drains under QK^T) -> conv (dwW now safe) -> softmax ->
// same-wave lgkmcnt fence for P -> PV from LDS -> epilogue.
// LDS = 40448 B -> 4 blocks/CU (16 waves/CU).
// ---------------------------------------------------------------------------
__global__ __launch_bounds__(256, 4) void stage2_mfma_kernel(
    const u16* __restrict__ q,
    const u16* __restrict__ agent,
    const u16* __restrict__ avt,
    const u16* __restrict__ v,
    const float* __restrict__ dwc_w,
    const float* __restrict__ dwc_b,
    u16* __restrict__ xattn)
{
    __shared__ __align__(16) u16 AVs[HD * AVP];       // avt [64][144]
    __shared__ __align__(16) u16 Pl[4 * 16 * S2PP];   // per-wave P tiles
    __shared__ float dwW[HD * 9];
    __shared__ float dwB[HD];

    const int h   = blockIdx.y;
    const int b   = blockIdx.z;
    const int tid = threadIdx.x;
    const int w    = tid >> 6;
    const int lane = tid & 63;
    const int c = lane & 15, g = lane >> 4;
    const int q0 = (blockIdx.x * 4 + w) * 16;     // 0..3120
    const int qg = q0 + c;
    const int y = qg / HHW, xx = qg % HHW;

    // Q fragment loads issued first
    const u16* qp = q + ((size_t)b * NTOK + qg) * CHN + h * HD + g * 8;
    bf16x8 qf0 = *reinterpret_cast<const bf16x8*>(qp);
    bf16x8 qf1 = *reinterpret_cast<const bf16x8*>(qp + 32);

    // ---- cooperative staging of avt + dw weights (drained at the barrier
    //      AFTER QK^T -- staging latency hides under the MFMA phase)
    {
        const u16* avb = avt + (size_t)(b * NH + h) * HD * NAG;
        for (int idx = tid; idx < HD * 18; idx += 256) {       // 1152 chunks
            const int r = idx / 18, cc = (idx % 18) * 8;
            *reinterpret_cast<u16x8*>(&AVs[r * AVP + cc]) =
                *reinterpret_cast<const u16x8*>(avb + (size_t)r * NAG + cc);
        }
        for (int idx = tid; idx < HD * 9; idx += 256)
            dwW[idx] = dwc_w[(h * HD + idx / 9) * 9 + (idx % 9)];
        if (tid < HD) dwB[tid] = dwc_b[h * HD + tid];
    }

    // ---- QK^T: S^T[agent][query], A-frags straight from global (L2-hot)
    f32x4 s[9] = {};
    const u16* ap = agent + ((size_t)b * NAG + c) * CHN + h * HD + g * 8;
    #pragma unroll
    for (int t = 0; t < 9; ++t) {
        bf16x8 af0 = *reinterpret_cast<const bf16x8*>(ap + (size_t)t * 16 * CHN);
        bf16x8 af1 = *reinterpret_cast<const bf16x8*>(ap + (size_t)t * 16 * CHN + 32);
        s[t] = __builtin_amdgcn_mfma_f32_16x16x32_bf16(af0, qf0, s[t], 0, 0, 0);
        s[t] = __builtin_amdgcn_mfma_f32_16x16x32_bf16(af1, qf1, s[t], 0, 0, 0);
    }

    // block barrier: drains AVs + dwW + dwB staging (hidden under QK^T)
    __syncthreads();

    // ---- depthwise conv: 36 independent clamped loads, consumed on arrival
    float conv[4][4];
    #pragma unroll
    for (int dt = 0; dt < 4; ++dt)
        #pragma unroll
        for (int r = 0; r < 4; ++r) conv[dt][r] = 0.f;
    {
        const u16* vq = v + ((size_t)b * NTOK + qg) * CHN + h * HD + g * 4;
        #pragma unroll
        for (int dy = -1; dy <= 1; ++dy) {
            #pragma unroll
            for (int dx = -1; dx <= 1; ++dx) {
                const int tap = (dy + 1) * 3 + (dx + 1);
                const int yy = y + dy, xc = xx + dx;
                const bool ok = (yy >= 0 && yy < HHW && xc >= 0 && xc < HHW);
                const u16* vr = vq + (ok ? (ptrdiff_t)(dy * HHW + dx) * CHN : 0);
                ushort4 vv0 = *reinterpret_cast<const ushort4*>(vr);
                ushort4 vv1 = *reinterpret_cast<const ushort4*>(vr + 16);
                ushort4 vv2 = *reinterpret_cast<const ushort4*>(vr + 32);
                ushort4 vv3 = *reinterpret_cast<const ushort4*>(vr + 48);
                if (ok) {
                    const float* wt = &dwW[(g * 4) * 9 + tap];
                    conv[0][0] += b2f(vv0.x) * wt[(0 * 16 + 0) * 9];
                    conv[0][1] += b2f(vv0.y) * wt[(0 * 16 + 1) * 9];
                    conv[0][2] += b2f(vv0.z) * wt[(0 * 16 + 2) * 9];
                    conv[0][3] += b2f(vv0.w) * wt[(0 * 16 + 3) * 9];
                    conv[1][0] += b2f(vv1.x) * wt[(1 * 16 + 0) * 9];
                    conv[1][1] += b2f(vv1.y) * wt[(1 * 16 + 1) * 9];
                    conv[1][2] += b2f(vv1.z) * wt[(1 * 16 + 2) * 9];
                    conv[1][3] += b2f(vv1.w) * wt[(1 * 16 + 3) * 9];
                    conv[2][0] += b2f(vv2.x) * wt[(2 * 16 + 0) * 9];
                    conv[2][1] += b2f(vv2.y) * wt[(2 * 16 + 1) * 9];
                    conv[2][2] += b2f(vv2.z) * wt[(2 * 16 + 2) * 9];
                    conv[2][3] += b2f(vv2.w) * wt[(2 * 16 + 3) * 9];
                    conv[3][0] += b2f(vv3.x) * wt[(3 * 16 + 0) * 9];
                    conv[3][1] += b2f(vv3.y) * wt[(3 * 16 + 1) * 9];
                    conv[3][2] += b2f(vv3.z) * wt[(3 * 16 + 2) * 9];
                    conv[3][3] += b2f(vv3.w) * wt[(3 * 16 + 3) * 9];
                }
            }
        }
    }

    // ---- softmax over agents: 36 in-lane + cross-g (xor 16,32)
    float mx = -1e30f;
    #pragma unroll
    for (int t = 0; t < 9; ++t)
        #pragma unroll
        for (int r = 0; r < 4; ++r) mx = fmaxf(mx, s[t][r]);
    mx = fmaxf(mx, __shfl_xor(mx, 16));
    mx = fmaxf(mx, __shfl_xor(mx, 32));
    mx *= 0.125f;

    u16* Pw = &Pl[w * 16 * S2PP];
    float ls = 0.f;
    #pragma unroll
    for (int t = 0; t < 9; ++t) {
        float p0 = __expf(s[t][0] * 0.125f - mx);
        float p1 = __expf(s[t][1] * 0.125f - mx);
        float p2 = __expf(s[t][2] * 0.125f - mx);
        float p3 = __expf(s[t][3] * 0.125f - mx);
        ls += (p0 + p1) + (p2 + p3);
        ushort4 pk;
        pk.x = f2b(p0); pk.y = f2b(p1); pk.z = f2b(p2); pk.w = f2b(p3);
        // P[query=c][agent=t*16+g*4 .. +3]
        *reinterpret_cast<ushort4*>(&Pw[c * S2PP + t * 16 + g * 4]) = pk;
    }
    ls += __shfl_xor(ls, 16);
    ls += __shfl_xor(ls, 32);
    const float inv = 1.f / ls;

    // same-wave LDS write->read ordering for the P tile
    asm volatile("s_waitcnt lgkmcnt(0)" ::: "memory");
    __builtin_amdgcn_sched_barrier(0);

    // ---- PV: O^T[d][query], AV-frags from LDS; 5th slice half-masked
    f32x4 o[4] = {};
    #pragma unroll
    for (int sl = 0; sl < 4; ++sl) {
        bf16x8 pf = *reinterpret_cast<const bf16x8*>(&Pw[c * S2PP + sl * 32 + g * 8]);
        #pragma unroll
        for (int dt = 0; dt < 4; ++dt) {
            bf16x8 avf = *reinterpret_cast<const bf16x8*>(
                &AVs[(dt * 16 + c) * AVP + sl * 32 + g * 8]);
            o[dt] = __builtin_amdgcn_mfma_f32_16x16x32_bf16(avf, pf, o[dt], 0, 0, 0);
        }
    }
    {   // slice 4: agents 128..143 live in lanes g<2; g>=2 contribute zeros
        bf16x8 pf = {};
        bf16x8 avf[4] = {{0,0,0,0,0,0,0,0},{0,0,0,0,0,0,0,0},
                         {0,0,0,0,0,0,0,0},{0,0,0,0,0,0,0,0}};
        if (g < 2) {
            pf = *reinterpret_cast<const bf16x8*>(&Pw[c * S2PP + 128 + g * 8]);
            #pragma unroll
            for (int dt = 0; dt < 4; ++dt)
                avf[dt] = *reinterpret_cast<const bf16x8*>(
                    &AVs[(dt * 16 + c) * AVP + 128 + g * 8]);
        }
        #pragma unroll
        for (int dt = 0; dt < 4; ++dt)
            o[dt] = __builtin_amdgcn_mfma_f32_16x16x32_bf16(avf[dt], pf, o[dt], 0, 0, 0);
    }

    // ---- epilogue: O^T[d=dt*16+g*4+r][query=qg]; + conv + bias + store
    u16* outp = xattn + ((size_t)b * NTOK + qg) * CHN + h * HD + g * 4;
    #pragma unroll
    for (int dt = 0; dt < 4; ++dt) {
        ushort4 o4;
        o4.x = f2b(o[dt][0] * inv + dwB[dt * 16 + g * 4 + 0] + conv[dt][0]);
        o4.y = f2b(o[dt][1] * inv + dwB[dt * 16 + g * 4 + 1] + conv[dt][1]);
        o4.z = f2b(o[dt][2] * inv + dwB[dt * 16 + g * 4 + 2] + conv[dt][2]);
        o4.w = f2b(o[dt][3] * inv + dwB[dt * 16 + g * 4 + 3] + conv[dt][3]);
        *reinterpret_cast<ushort4*>(outp + dt * 16) = o4;
    }
}

// ---------------------------------------------------------------------------
extern "C" void kernel_launch(void* const* d_in, const int* in_sizes, int n_in,
                              void* d_out, int out_size, void* d_ws, size_t ws_size,
                              hipStream_t stream)
{
    const float* x      = (const float*)d_in[0];
    const float* qkv_w  = (const float*)d_in[1];
    const float* proj_w = (const float*)d_in[2];
    const float* proj_b = (const float*)d_in[3];
    const float* dwc_w  = (const float*)d_in[4];
    const float* dwc_b  = (const float*)d_in[5];
    float* out = (float*)d_out;

    const size_t nqkv = (size_t)BATCH * NTOK * CHN;       // 25,690,112
    // Buffer choreography (all race-free by stream order):
    //   d_out.lo: xb (bf16 x) until q-GEMM; then dead; final proj writes fp32
    //             over full d_out.
    //   d_out.hi: Vt (v transposed, for stage-1), then q after stage-1.
    //   x.lo:     k (bf16), then attn (k dead after stage-1)
    //   x.hi:     v (bf16)
    u16* xb  = (u16*)d_out;           // bf16 x
    u16* vt  = xb + nqkv;             // Vt [b][512][3136] (d_out.hi)
    u16* qb  = xb + nqkv;             // q, same region, after stage-1
    u16* kb  = (u16*)d_in[0];         // k  (x buffer lower half)
    u16* vb  = kb + nqkv;             // v  (x buffer upper half)
    u16* attn = kb;                   // attn overwrites k (dead after stage1)

    // ws: x_pool/agent/avt (3 x 2,359,296 B) + wb (2,097,152 B) = 9.18 MB
    char* p = (char*)d_ws;
    u16* x_pool  = (u16*)p;  p += (size_t)BATCH * NAG * CHN * 2;
    u16* agent   = (u16*)p;  p += (size_t)BATCH * NAG * CHN * 2;
    u16* avt     = (u16*)p;  p += (size_t)BATCH * NH * HD * NAG * 2;
    u16* wb      = (u16*)p;           // qkv_w (786432) + proj_w (262144) bf16
    u16* Wq_b = wb;
    u16* Wk_b = wb + (size_t)262144;
    u16* Wv_b = wb + (size_t)524288;
    u16* Wp_b = wb + (size_t)786432;

    // 1. pool x (fp32, exact) -> x_pool bf16      [reads x]
    pool_x_kernel<<<dim3(BATCH, NAG), 256, 0, stream>>>(x, x_pool);
    // 2. convert x -> xb (d_out.lo)               [reads x]
    cvt_f32_bf16_kernel<<<(int)(nqkv / 4 + 255) / 256, 256, 0, stream>>>(x, xb, (int)(nqkv / 4));
    // 3. convert weights -> wb
    cvt_f32_bf16_kernel<<<(786432 / 4 + 255) / 256, 256, 0, stream>>>(qkv_w, wb, 786432 / 4);
    cvt_f32_bf16_kernel<<<(262144 / 4 + 255) / 256, 256, 0, stream>>>(proj_w, Wp_b, 262144 / 4);
    // 4. agent = x_pool @ Wq^T  (M = 2304)
    mfma_gemm_kernel<u16, false><<<dim3(18, 4), 256, 0, stream>>>(x_pool, Wq_b, nullptr, agent);
    // 5. k = xb @ Wk^T -> x.lo  (x fp32 fully consumed by 1&2)
    mfma_gemm_kernel<u16, false><<<dim3(392, 4), 256, 0, stream>>>(xb, Wk_b, nullptr, kb);
    // 6. v = xb @ Wv^T -> x.hi
    mfma_gemm_kernel<u16, false><<<dim3(392, 4), 256, 0, stream>>>(xb, Wv_b, nullptr, vb);
    // 7. Vt = v^T -> d_out.hi (per batch: [512][3136])
    transpose_v_kernel<<<dim3(NTOK / 64, CHN / 64, BATCH), 256, 0, stream>>>(vb, vt);
    // 8. stage-1 flash attention (MFMA) -> avt [b][h][d][144]
    stage1_mfma_kernel<<<dim3(1152), 64, 0, stream>>>(kb, vt, agent, avt);
    // 9. q = xb @ Wq^T -> d_out.hi (Vt dead; xb dead afterwards)
    mfma_gemm_kernel<u16, false><<<dim3(392, 4), 256, 0, stream>>>(xb, Wq_b, nullptr, qb);
    // 10. stage-2 MFMA + dw conv -> attn (x.lo; k dead, disjoint from q/v)
    stage2_mfma_kernel<<<dim3(49, NH, BATCH), 256, 0, stream>>>(
        qb, agent, avt, vb, dwc_w, dwc_b, attn);
    // 11. out = attn @ proj_w^T + proj_b -> full d_out fp32 (xb,q dead)
    mfma_gemm_kernel<float, true><<<dim3(392, 4), 256, 0, stream>>>(attn, Wp_b, proj_b, out);
}

// Round 13
// 728.594 us; speedup vs baseline: 1.0356x; 1.0356x over previous
//
#include <hip/hip_runtime.h>
#include <hip/hip_bf16.h>
#include <math.h>

typedef unsigned short u16;
typedef __attribute__((ext_vector_type(8))) unsigned short u16x8;
typedef __attribute__((ext_vector_type(8))) short bf16x8;
typedef __attribute__((ext_vector_type(4))) float f32x4;

#define BATCH 16
#define NTOK  3136
#define CHN   512
#define NH    8
#define HD    64
#define HHW   56
#define NAG   144
#define PS    12

#define S1PP   72      // stage-1 P-tile pitch (u16)
#define S2PP   152     // stage-2 P-tile pitch (u16)
#define ASP    72      // stage-2 agent LDS pitch
#define AVP    152     // stage-2 avt LDS pitch

__device__ __forceinline__ float b2f(u16 u) {
    unsigned int x = ((unsigned int)u) << 16;
    float f;
    __builtin_memcpy(&f, &x, 4);
    return f;
}
__device__ __forceinline__ u16 f2b(float f) {
    unsigned int x;
    __builtin_memcpy(&x, &f, 4);
    unsigned int lsb = (x >> 16) & 1u;
    x += 0x7fffu + lsb;            // round-to-nearest-even (finite values)
    return (u16)(x >> 16);
}
__device__ __forceinline__ void store1(float* p, float v) { *p = v; }
__device__ __forceinline__ void store1(u16* p, float v)   { *p = f2b(v); }

// ---------------------------------------------------------------------------
// fp32 -> bf16 conversion (vectorized, memory-bound)
// ---------------------------------------------------------------------------
__global__ __launch_bounds__(256) void cvt_f32_bf16_kernel(
    const float* __restrict__ src, u16* __restrict__ dst, int n4)
{
    const int idx = blockIdx.x * 256 + threadIdx.x;
    if (idx >= n4) return;
    float4 v = reinterpret_cast<const float4*>(src)[idx];
    ushort4 o;
    o.x = f2b(v.x); o.y = f2b(v.y); o.z = f2b(v.z); o.w = f2b(v.w);
    reinterpret_cast<ushort4*>(dst)[idx] = o;
}

// ---------------------------------------------------------------------------
// MFMA GEMM (m97 pattern): out[m,n] = A[m,:].W[n,:] (+bias), K=512, N=512.
// ---------------------------------------------------------------------------
template <typename OT, bool BIAS>
__global__ __launch_bounds__(256) void mfma_gemm_kernel(
    const u16* __restrict__ A, const u16* __restrict__ W,
    const float* __restrict__ bias, OT* __restrict__ out)
{
    __shared__ u16 Asm[128 * 64];
    __shared__ u16 Bsm[128 * 64];

    const int tid  = threadIdx.x;
    const int lane = tid & 63;
    const int w    = tid >> 6;          // wave 0..3
    const int m0   = blockIdx.x * 128;
    const int n0   = blockIdx.y * 128;
    const int wm   = (w & 1) * 64;      // wave row offset in tile
    const int wn   = (w >> 1) * 64;     // wave col offset in tile

    const int srow = lane >> 3;         // staging row within 8-row chunk
    const int scol = (lane & 7) * 8;    // staging k-offset (elems)

    f32x4 acc[4][4] = {};

    for (int kt = 0; kt < 8; ++kt) {
        const int k0 = kt * 64;
        __syncthreads();                 // LDS free (prev iter's reads done)
        #pragma unroll
        for (int i = 0; i < 4; ++i) {
            const int rb = w * 8 + i * 32;
            __builtin_amdgcn_global_load_lds(
                (const __attribute__((address_space(1))) void*)
                    (A + (size_t)(m0 + rb + srow) * 512 + k0 + scol),
                (__attribute__((address_space(3))) void*)(Asm + rb * 64),
                16, 0, 0);
        }
        #pragma unroll
        for (int i = 0; i < 4; ++i) {
            const int rb = w * 8 + i * 32;
            __builtin_amdgcn_global_load_lds(
                (const __attribute__((address_space(1))) void*)
                    (W + (size_t)(n0 + rb + srow) * 512 + k0 + scol),
                (__attribute__((address_space(3))) void*)(Bsm + rb * 64),
                16, 0, 0);
        }
        __syncthreads();                 // staging complete

        #pragma unroll
        for (int kh = 0; kh < 2; ++kh) {
            bf16x8 af[4], bfr[4];
            #pragma unroll
            for (int t = 0; t < 4; ++t)
                af[t] = *reinterpret_cast<const bf16x8*>(
                    &Asm[(wm + t * 16 + (lane & 15)) * 64 + kh * 32 + (lane >> 4) * 8]);
            #pragma unroll
            for (int t = 0; t < 4; ++t)
                bfr[t] = *reinterpret_cast<const bf16x8*>(
                    &Bsm[(wn + t * 16 + (lane & 15)) * 64 + kh * 32 + (lane >> 4) * 8]);
            #pragma unroll
            for (int i = 0; i < 4; ++i)
                #pragma unroll
                for (int j = 0; j < 4; ++j)
                    acc[i][j] = __builtin_amdgcn_mfma_f32_16x16x32_bf16(
                        af[i], bfr[j], acc[i][j], 0, 0, 0);
        }
    }

    // epilogue: C/D layout col=lane&15, row=(lane>>4)*4+reg  [m89/m91]
    const int quad = lane >> 4;
    const int col  = lane & 15;
    #pragma unroll
    for (int j = 0; j < 4; ++j) {
        const int n = n0 + wn + j * 16 + col;
        const float bv = BIAS ? bias[n] : 0.f;
        #pragma unroll
        for (int i = 0; i < 4; ++i) {
            #pragma unroll
            for (int r = 0; r < 4; ++r) {
                const int m = m0 + wm + i * 16 + quad * 4 + r;
                store1(&out[(size_t)m * 512 + n], acc[i][j][r] + bv);
            }
        }
    }
}

// ---------------------------------------------------------------------------
// Adaptive avg-pool x (b,56,56,c) fp32 -> x_pool (b,144,c) bf16.
// ---------------------------------------------------------------------------
__global__ __launch_bounds__(256) void pool_x_kernel(
    const float* __restrict__ x, u16* __restrict__ x_pool)
{
    const int b = blockIdx.x, pq = blockIdx.y;
    const int p = pq / PS, qq = pq % PS;
    const int sp_ = (p * HHW) / PS, ep_ = ((p + 1) * HHW + PS - 1) / PS;
    const int sq_ = (qq * HHW) / PS, eq_ = ((qq + 1) * HHW + PS - 1) / PS;
    const float inv = 1.0f / (float)((ep_ - sp_) * (eq_ - sq_));
    for (int ch = threadIdx.x; ch < CHN; ch += 256) {
        float acc = 0.f;
        for (int y = sp_; y < ep_; ++y)
            for (int xx = sq_; xx < eq_; ++xx)
                acc += x[((size_t)b * NTOK + y * HHW + xx) * CHN + ch];
        x_pool[((size_t)b * NAG + pq) * CHN + ch] = f2b(acc * inv);
    }
}

// ---------------------------------------------------------------------------
// v (b,tok,512) bf16 -> vt (b,512,tok) bf16.  64x64 LDS tiles, skewed pitch.
// ---------------------------------------------------------------------------
__global__ __launch_bounds__(256) void transpose_v_kernel(
    const u16* __restrict__ v, u16* __restrict__ vt)
{
    __shared__ u16 T[64 * S1PP + 32];
    const int t0 = blockIdx.x * 64;      // token tile
    const int c0 = blockIdx.y * 64;      // channel tile
    const int b  = blockIdx.z;

    const int r  = threadIdx.x >> 2;           // token row 0..63
    const int cc = (threadIdx.x & 3) * 16;     // channel offset {0,16,32,48}
    const u16* src = v + ((size_t)b * NTOK + t0 + r) * CHN + c0 + cc;
    u16x8 a0 = *reinterpret_cast<const u16x8*>(src);
    u16x8 a1 = *reinterpret_cast<const u16x8*>(src + 8);
    const int skw = (cc >> 4) * 8;             // bank skew, keeps 16B alignment
    #pragma unroll
    for (int j = 0; j < 8; ++j) T[(cc + j) * S1PP + r + skw] = a0[j];
    #pragma unroll
    for (int j = 0; j < 8; ++j) T[(cc + 8 + j) * S1PP + r + skw] = a1[j];
    __syncthreads();

    const int cr  = threadIdx.x >> 2;          // channel row 0..63
    const int tt  = (threadIdx.x & 3) * 16;    // token offset
    const int rsk = (cr >> 4) * 8;
    u16* dst = vt + ((size_t)b * CHN + c0 + cr) * NTOK + t0 + tt;
    *reinterpret_cast<u16x8*>(dst)     = *reinterpret_cast<const u16x8*>(&T[cr * S1PP + tt + rsk]);
    *reinterpret_cast<u16x8*>(dst + 8) = *reinterpret_cast<const u16x8*>(&T[cr * S1PP + tt + 8 + rsk]);
}

// ---------------------------------------------------------------------------
// Stage-1 flash attention, MFMA version (unchanged).
// ---------------------------------------------------------------------------
__global__ __launch_bounds__(64) void stage1_mfma_kernel(
    const u16* __restrict__ k, const u16* __restrict__ vt,
    const u16* __restrict__ agent, u16* __restrict__ avt)
{
    __shared__ u16 Pl[16 * S1PP];

    const int lb   = blockIdx.x;
    const int work = (lb & 7) * 144 + (lb >> 3);  // bijective XCD swizzle (1152%8==0)
    const int at   = work % 9;                    // agent tile 0..8
    const int r2   = work / 9;
    const int h    = r2 & 7;
    const int b    = r2 >> 3;

    const int lane = threadIdx.x;
    const int c = lane & 15, g = lane >> 4;

    const u16* kp = k  + (size_t)b * NTOK * CHN + h * HD;
    const u16* vp = vt + ((size_t)(b * NH + h)) * HD * NTOK;
    const u16* ap = agent + ((size_t)b * NAG + at * 16 + c) * CHN + h * HD + g * 8;

    // A (agent) fragments resident in registers: rows=agents, k=d
    bf16x8 af0 = *reinterpret_cast<const bf16x8*>(ap);
    bf16x8 af1 = *reinterpret_cast<const bf16x8*>(ap + 32);

    f32x4 accO[4] = {};                 // O^T, d-tiles 0..3
    float m_ = -1e30f, l_ = 0.f;

    // prologue: K fragments for tile 0 (rows=keys, k=d)
    bf16x8 kf[8];
    #pragma unroll
    for (int kt = 0; kt < 4; ++kt)
        #pragma unroll
        for (int ks = 0; ks < 2; ++ks)
            kf[kt * 2 + ks] = *reinterpret_cast<const bf16x8*>(
                kp + (size_t)(kt * 16 + c) * CHN + ks * 32 + g * 8);

    for (int key0 = 0; key0 < NTOK; key0 += 64) {
        // issue current-tile Vt frags (rows=d, k=keys) + next-tile K frags
        bf16x8 vf[8];
        #pragma unroll
        for (int dt = 0; dt < 4; ++dt)
            #pragma unroll
            for (int kk = 0; kk < 2; ++kk)
                vf[dt * 2 + kk] = *reinterpret_cast<const bf16x8*>(
                    vp + (size_t)(dt * 16 + c) * NTOK + key0 + kk * 32 + g * 8);
        bf16x8 kn[8];
        const bool more = (key0 + 64) < NTOK;
        if (more) {
            #pragma unroll
            for (int kt = 0; kt < 4; ++kt)
                #pragma unroll
                for (int ks = 0; ks < 2; ++ks)
                    kn[kt * 2 + ks] = *reinterpret_cast<const bf16x8*>(
                        kp + (size_t)(key0 + 64 + kt * 16 + c) * CHN + ks * 32 + g * 8);
        }

        // S^T tiles: D[key][agent]
        f32x4 s[4] = {};
        #pragma unroll
        for (int kt = 0; kt < 4; ++kt) {
            s[kt] = __builtin_amdgcn_mfma_f32_16x16x32_bf16(kf[kt * 2 + 0], af0, s[kt], 0, 0, 0);
            s[kt] = __builtin_amdgcn_mfma_f32_16x16x32_bf16(kf[kt * 2 + 1], af1, s[kt], 0, 0, 0);
        }

        // online softmax: keys are in-lane (16 vals) + across g groups (xor 16,32)
        float tmax = -1e30f;
        #pragma unroll
        for (int kt = 0; kt < 4; ++kt)
            #pragma unroll
            for (int r = 0; r < 4; ++r) tmax = fmaxf(tmax, s[kt][r]);
        tmax = fmaxf(tmax, __shfl_xor(tmax, 16));
        tmax = fmaxf(tmax, __shfl_xor(tmax, 32));

        const float mnew  = fmaxf(m_, tmax * 0.125f);   // scale=1/8 folded here
        const float alpha = __expf(m_ - mnew);
        float psum = 0.f;
        #pragma unroll
        for (int kt = 0; kt < 4; ++kt) {
            float p0 = __expf(s[kt][0] * 0.125f - mnew);
            float p1 = __expf(s[kt][1] * 0.125f - mnew);
            float p2 = __expf(s[kt][2] * 0.125f - mnew);
            float p3 = __expf(s[kt][3] * 0.125f - mnew);
            psum += (p0 + p1) + (p2 + p3);
            ushort4 pk;
            pk.x = f2b(p0); pk.y = f2b(p1); pk.z = f2b(p2); pk.w = f2b(p3);
            // P[agent=c][key=kt*16+g*4 .. +3]
            *reinterpret_cast<ushort4*>(&Pl[c * S1PP + kt * 16 + g * 4]) = pk;
        }
        psum += __shfl_xor(psum, 16);
        psum += __shfl_xor(psum, 32);
        l_ = l_ * alpha + psum;
        m_ = mnew;
        #pragma unroll
        for (int dt = 0; dt < 4; ++dt) {
            accO[dt][0] *= alpha; accO[dt][1] *= alpha;
            accO[dt][2] *= alpha; accO[dt][3] *= alpha;
        }

        // cross-lane LDS write->read within the wave: force ordering
        asm volatile("s_waitcnt lgkmcnt(0)" ::: "memory");
        __builtin_amdgcn_sched_barrier(0);

        bf16x8 pf0 = *reinterpret_cast<const bf16x8*>(&Pl[c * S1PP + g * 8]);
        bf16x8 pf1 = *reinterpret_cast<const bf16x8*>(&Pl[c * S1PP + 32 + g * 8]);

        #pragma unroll
        for (int dt = 0; dt < 4; ++dt) {
            accO[dt] = __builtin_amdgcn_mfma_f32_16x16x32_bf16(vf[dt * 2 + 0], pf0, accO[dt], 0, 0, 0);
            accO[dt] = __builtin_amdgcn_mfma_f32_16x16x32_bf16(vf[dt * 2 + 1], pf1, accO[dt], 0, 0, 0);
        }

        if (more) {
            #pragma unroll
            for (int i = 0; i < 8; ++i) kf[i] = kn[i];
        }
    }

    // epilogue: lane holds O^T[d=dt*16+g*4+r][agent=at*16+c] -> write avt
    const float invl = 1.f / l_;
    const size_t dbase = (size_t)(b * NH + h) * HD;
    #pragma unroll
    for (int dt = 0; dt < 4; ++dt)
        #pragma unroll
        for (int r = 0; r < 4; ++r)
            avt[(dbase + dt * 16 + g * 4 + r) * NAG + at * 16 + c] =
                f2b(accO[dt][r] * invl);
}

// ---------------------------------------------------------------------------
// Stage-2 attention, MFMA + LDS-staged operands + fused depthwise conv.
// r7 structure (best measured: 158 us) with ONE change: Pl aliases As
// (As dead after QK^T; barrier #2 closes the cross-wave WAR), cutting LDS
// 62464 -> 42752 B => 3 blocks/CU (12 waves/CU, +50% occupancy).
// ---------------------------------------------------------------------------
__global__ __launch_bounds__(256, 3) void stage2_mfma_kernel(
    const u16* __restrict__ q,
    const u16* __restrict__ agent,
    const u16* __restrict__ avt,
    const u16* __restrict__ v,
    const float* __restrict__ dwc_w,
    const float* __restrict__ dwc_b,
    u16* __restrict__ xattn)
{
    // As (144x72 = 20736 B, dead after QK^T) overlaps Pl (4x16x152 = 19456 B)
    __shared__ __align__(16) u16 AsPl[NAG * ASP];
    __shared__ __align__(16) u16 AVs[HD * AVP];       // avt [64][144] p=152
    __shared__ float dwW[HD * 9];
    __shared__ float dwB[HD];

    const int h   = blockIdx.y;
    const int b   = blockIdx.z;
    const int tid = threadIdx.x;
    const int w    = tid >> 6;
    const int lane = tid & 63;
    const int c = lane & 15, g = lane >> 4;
    const int q0 = (blockIdx.x * 4 + w) * 16;     // 0..3120
    const int qg = q0 + c;
    const int y = qg / HHW, xx = qg % HHW;

    // Q fragment loads issued first (latency hides under staging)
    const u16* qp = q + ((size_t)b * NTOK + qg) * CHN + h * HD + g * 8;
    bf16x8 qf0 = *reinterpret_cast<const bf16x8*>(qp);
    bf16x8 qf1 = *reinterpret_cast<const bf16x8*>(qp + 32);

    // ---- cooperative staging: agent + avt + dw weights
    {
        const u16* ab = agent + (size_t)b * NAG * CHN + h * HD;
        for (int idx = tid; idx < NAG * 4; idx += 256) {       // 576 chunks
            const int r = idx >> 2, cc = (idx & 3) * 16;
            *reinterpret_cast<u16x8*>(&AsPl[r * ASP + cc]) =
                *reinterpret_cast<const u16x8*>(ab + (size_t)r * CHN + cc);
            *reinterpret_cast<u16x8*>(&AsPl[r * ASP + cc + 8]) =
                *reinterpret_cast<const u16x8*>(ab + (size_t)r * CHN + cc + 8);
        }
        const u16* avb = avt + (size_t)(b * NH + h) * HD * NAG;
        for (int idx = tid; idx < HD * 18; idx += 256) {       // 1152 chunks
            const int r = idx / 18, cc = (idx % 18) * 8;
            *reinterpret_cast<u16x8*>(&AVs[r * AVP + cc]) =
                *reinterpret_cast<const u16x8*>(avb + (size_t)r * NAG + cc);
        }
        for (int idx = tid; idx < HD * 9; idx += 256)
            dwW[idx] = dwc_w[(h * HD + idx / 9) * 9 + (idx % 9)];
        if (tid < HD) dwB[tid] = dwc_b[h * HD + tid];
    }
    __syncthreads();

    // ---- depthwise conv: 36 independent clamped loads, consumed on arrival
    float conv[4][4];
    #pragma unroll
    for (int dt = 0; dt < 4; ++dt)
        #pragma unroll
        for (int r = 0; r < 4; ++r) conv[dt][r] = 0.f;
    {
        const u16* vq = v + ((size_t)b * NTOK + qg) * CHN + h * HD + g * 4;
        #pragma unroll
        for (int dy = -1; dy <= 1; ++dy) {
            #pragma unroll
            for (int dx = -1; dx <= 1; ++dx) {
                const int tap = (dy + 1) * 3 + (dx + 1);
                const int yy = y + dy, xc = xx + dx;
                const bool ok = (yy >= 0 && yy < HHW && xc >= 0 && xc < HHW);
                const u16* vr = vq + (ok ? (ptrdiff_t)(dy * HHW + dx) * CHN : 0);
                ushort4 vv0 = *reinterpret_cast<const ushort4*>(vr);
                ushort4 vv1 = *reinterpret_cast<const ushort4*>(vr + 16);
                ushort4 vv2 = *reinterpret_cast<const ushort4*>(vr + 32);
                ushort4 vv3 = *reinterpret_cast<const ushort4*>(vr + 48);
                if (ok) {
                    const float* wt = &dwW[(g * 4) * 9 + tap];
                    conv[0][0] += b2f(vv0.x) * wt[(0 * 16 + 0) * 9];
                    conv[0][1] += b2f(vv0.y) * wt[(0 * 16 + 1) * 9];
                    conv[0][2] += b2f(vv0.z) * wt[(0 * 16 + 2) * 9];
                    conv[0][3] += b2f(vv0.w) * wt[(0 * 16 + 3) * 9];
                    conv[1][0] += b2f(vv1.x) * wt[(1 * 16 + 0) * 9];
                    conv[1][1] += b2f(vv1.y) * wt[(1 * 16 + 1) * 9];
                    conv[1][2] += b2f(vv1.z) * wt[(1 * 16 + 2) * 9];
                    conv[1][3] += b2f(vv1.w) * wt[(1 * 16 + 3) * 9];
                    conv[2][0] += b2f(vv2.x) * wt[(2 * 16 + 0) * 9];
                    conv[2][1] += b2f(vv2.y) * wt[(2 * 16 + 1) * 9];
                    conv[2][2] += b2f(vv2.z) * wt[(2 * 16 + 2) * 9];
                    conv[2][3] += b2f(vv2.w) * wt[(2 * 16 + 3) * 9];
                    conv[3][0] += b2f(vv3.x) * wt[(3 * 16 + 0) * 9];
                    conv[3][1] += b2f(vv3.y) * wt[(3 * 16 + 1) * 9];
                    conv[3][2] += b2f(vv3.z) * wt[(3 * 16 + 2) * 9];
                    conv[3][3] += b2f(vv3.w) * wt[(3 * 16 + 3) * 9];
                }
            }
        }
    }

    // ---- QK^T: S^T[agent][query], 9 agent tiles (A-frags from LDS)
    f32x4 s[9] = {};
    #pragma unroll
    for (int t = 0; t < 9; ++t) {
        bf16x8 af0 = *reinterpret_cast<const bf16x8*>(&AsPl[(t * 16 + c) * ASP + g * 8]);
        bf16x8 af1 = *reinterpret_cast<const bf16x8*>(&AsPl[(t * 16 + c) * ASP + 32 + g * 8]);
        s[t] = __builtin_amdgcn_mfma_f32_16x16x32_bf16(af0, qf0, s[t], 0, 0, 0);
        s[t] = __builtin_amdgcn_mfma_f32_16x16x32_bf16(af1, qf1, s[t], 0, 0, 0);
    }

    // barrier #2: all waves done reading As before Pl overwrites it (WAR)
    __syncthreads();

    // ---- softmax over agents: 36 in-lane + cross-g (xor 16,32)
    float mx = -1e30f;
    #pragma unroll
    for (int t = 0; t < 9; ++t)
        #pragma unroll
        for (int r = 0; r < 4; ++r) mx = fmaxf(mx, s[t][r]);
    mx = fmaxf(mx, __shfl_xor(mx, 16));
    mx = fmaxf(mx, __shfl_xor(mx, 32));
    mx *= 0.125f;

    u16* Pw = &AsPl[w * 16 * S2PP];     // Pl aliases As (dead)
    float ls = 0.f;
    #pragma unroll
    for (int t = 0; t < 9; ++t) {
        float p0 = __expf(s[t][0] * 0.125f - mx);
        float p1 = __expf(s[t][1] * 0.125f - mx);
        float p2 = __expf(s[t][2] * 0.125f - mx);
        float p3 = __expf(s[t][3] * 0.125f - mx);
        ls += (p0 + p1) + (p2 + p3);
        ushort4 pk;
        pk.x = f2b(p0); pk.y = f2b(p1); pk.z = f2b(p2); pk.w = f2b(p3);
        // P[query=c][agent=t*16+g*4 .. +3]
        *reinterpret_cast<ushort4*>(&Pw[c * S2PP + t * 16 + g * 4]) = pk;
    }
    ls += __shfl_xor(ls, 16);
    ls += __shfl_xor(ls, 32);
    const float inv = 1.f / ls;

    // same-wave LDS write->read ordering for the P tile
    asm volatile("s_waitcnt lgkmcnt(0)" ::: "memory");
    __builtin_amdgcn_sched_barrier(0);

    // ---- PV: O^T[d][query], AV-frags from LDS; 5th slice half-masked
    f32x4 o[4] = {};
    #pragma unroll
    for (int sl = 0; sl < 4; ++sl) {
        bf16x8 pf = *reinterpret_cast<const bf16x8*>(&Pw[c * S2PP + sl * 32 + g * 8]);
        #pragma unroll
        for (int dt = 0; dt < 4; ++dt) {
            bf16x8 avf = *reinterpret_cast<const bf16x8*>(
                &AVs[(dt * 16 + c) * AVP + sl * 32 + g * 8]);
            o[dt] = __builtin_amdgcn_mfma_f32_16x16x32_bf16(avf, pf, o[dt], 0, 0, 0);
        }
    }
    {   // slice 4: agents 128..143 live in lanes g<2; g>=2 contribute zeros
        bf16x8 pf = {};
        bf16x8 avf[4] = {{0,0,0,0,0,0,0,0},{0,0,0,0,0,0,0,0},
                         {0,0,0,0,0,0,0,0},{0,0,0,0,0,0,0,0}};
        if (g < 2) {
            pf = *reinterpret_cast<const bf16x8*>(&Pw[c * S2PP + 128 + g * 8]);
            #pragma unroll
            for (int dt = 0; dt < 4; ++dt)
                avf[dt] = *reinterpret_cast<const bf16x8*>(
                    &AVs[(dt * 16 + c) * AVP + 128 + g * 8]);
        }
        #pragma unroll
        for (int dt = 0; dt < 4; ++dt)
            o[dt] = __builtin_amdgcn_mfma_f32_16x16x32_bf16(avf[dt], pf, o[dt], 0, 0, 0);
    }

    // ---- epilogue: O^T[d=dt*16+g*4+r][query=qg]; + conv + bias + store
    u16* outp = xattn + ((size_t)b * NTOK + qg) * CHN + h * HD + g * 4;
    #pragma unroll
    for (int dt = 0; dt < 4; ++dt) {
        ushort4 o4;
        o4.x = f2b(o[dt][0] * inv + dwB[dt * 16 + g * 4 + 0] + conv[dt][0]);
        o4.y = f2b(o[dt][1] * inv + dwB[dt * 16 + g * 4 + 1] + conv[dt][1]);
        o4.z = f2b(o[dt][2] * inv + dwB[dt * 16 + g * 4 + 2] + conv[dt][2]);
        o4.w = f2b(o[dt][3] * inv + dwB[dt * 16 + g * 4 + 3] + conv[dt][3]);
        *reinterpret_cast<ushort4*>(outp + dt * 16) = o4;
    }
}

// ---------------------------------------------------------------------------
extern "C" void kernel_launch(void* const* d_in, const int* in_sizes, int n_in,
                              void* d_out, int out_size, void* d_ws, size_t ws_size,
                              hipStream_t stream)
{
    const float* x      = (const float*)d_in[0];
    const float* qkv_w  = (const float*)d_in[1];
    const float* proj_w = (const float*)d_in[2];
    const float* proj_b = (const float*)d_in[3];
    const float* dwc_w  = (const float*)d_in[4];
    const float* dwc_b  = (const float*)d_in[5];
    float* out = (float*)d_out;

    const size_t nqkv = (size_t)BATCH * NTOK * CHN;       // 25,690,112
    // Buffer choreography (all race-free by stream order):
    //   d_out.lo: xb (bf16 x) until q-GEMM; then dead; final proj writes fp32
    //             over full d_out.
    //   d_out.hi: Vt (v transposed, for stage-1), then q after stage-1.
    //   x.lo:     k (bf16), then attn (k dead after stage-1)
    //   x.hi:     v (bf16)
    u16* xb  = (u16*)d_out;           // bf16 x
    u16* vt  = xb + nqkv;             // Vt [b][512][3136] (d_out.hi)
    u16* qb  = xb + nqkv;             // q, same region, after stage-1
    u16* kb  = (u16*)d_in[0];         // k  (x buffer lower half)
    u16* vb  = kb + nqkv;             // v  (x buffer upper half)
    u16* attn = kb;                   // attn overwrites k (dead after stage1)

    // ws: x_pool/agent/avt (3 x 2,359,296 B) + wb (2,097,152 B) = 9.18 MB
    char* p = (char*)d_ws;
    u16* x_pool  = (u16*)p;  p += (size_t)BATCH * NAG * CHN * 2;
    u16* agent   = (u16*)p;  p += (size_t)BATCH * NAG * CHN * 2;
    u16* avt     = (u16*)p;  p += (size_t)BATCH * NH * HD * NAG * 2;
    u16* wb      = (u16*)p;           // qkv_w (786432) + proj_w (262144) bf16
    u16* Wq_b = wb;
    u16* Wk_b = wb + (size_t)262144;
    u16* Wv_b = wb + (size_t)524288;
    u16* Wp_b = wb + (size_t)786432;

    // 1. pool x (fp32, exact) -> x_pool bf16      [reads x]
    pool_x_kernel<<<dim3(BATCH, NAG), 256, 0, stream>>>(x, x_pool);
    // 2. convert x -> xb (d_out.lo)               [reads x]
    cvt_f32_bf16_kernel<<<(int)(nqkv / 4 + 255) / 256, 256, 0, stream>>>(x, xb, (int)(nqkv / 4));
    // 3. convert weights -> wb
    cvt_f32_bf16_kernel<<<(786432 / 4 + 255) / 256, 256, 0, stream>>>(qkv_w, wb, 786432 / 4);
    cvt_f32_bf16_kernel<<<(262144 / 4 + 255) / 256, 256, 0, stream>>>(proj_w, Wp_b, 262144 / 4);
    // 4. agent = x_pool @ Wq^T  (M = 2304)
    mfma_gemm_kernel<u16, false><<<dim3(18, 4), 256, 0, stream>>>(x_pool, Wq_b, nullptr, agent);
    // 5. k = xb @ Wk^T -> x.lo  (x fp32 fully consumed by 1&2)
    mfma_gemm_kernel<u16, false><<<dim3(392, 4), 256, 0, stream>>>(xb, Wk_b, nullptr, kb);
    // 6. v = xb @ Wv^T -> x.hi
    mfma_gemm_kernel<u16, false><<<dim3(392, 4), 256, 0, stream>>>(xb, Wv_b, nullptr, vb);
    // 7. Vt = v^T -> d_out.hi (per batch: [512][3136])
    transpose_v_kernel<<<dim3(NTOK / 64, CHN / 64, BATCH), 256, 0, stream>>>(vb, vt);
    // 8. stage-1 flash attention (MFMA) -> avt [b][h][d][144]
    stage1_mfma_kernel<<<dim3(1152), 64, 0, stream>>>(kb, vt, agent, avt);
    // 9. q = xb @ Wq^T -> d_out.hi (Vt dead; xb dead afterwards)
    mfma_gemm_kernel<u16, false><<<dim3(392, 4), 256, 0, stream>>>(xb, Wq_b, nullptr, qb);
    // 10. stage-2 MFMA + dw conv -> attn (x.lo; k dead, disjoint from q/v)
    stage2_mfma_kernel<<<dim3(49, NH, BATCH), 256, 0, stream>>>(
        qb, agent, avt, vb, dwc_w, dwc_b, attn);
    // 11. out = attn @ proj_w^T + proj_b -> full d_out fp32 (xb,q dead)
    mfma_gemm_kernel<float, true><<<dim3(392, 4), 256, 0, stream>>>(attn, Wp_b, proj_b, out);
}

// Round 14
// 711.428 us; speedup vs baseline: 1.0606x; 1.0241x over previous
//
#include <hip/hip_runtime.h>
#include <hip/hip_bf16.h>
#include <math.h>

typedef unsigned short u16;
typedef __attribute__((ext_vector_type(8))) unsigned short u16x8;
typedef __attribute__((ext_vector_type(8))) short bf16x8;
typedef __attribute__((ext_vector_type(4))) float f32x4;

#define BATCH 16
#define NTOK  3136
#define CHN   512
#define NH    8
#define HD    64
#define HHW   56
#define NAG   144
#define PS    12

#define S1PP   72      // stage-1 P-tile pitch (u16)
#define S2PP   152     // stage-2 P-tile pitch (u16)
#define ASP    72      // stage-2 agent LDS pitch
#define AVP    152     // stage-2 avt LDS pitch
#define TRP    136     // v-GEMM transpose bounce pitch (u16), mult of 8

__device__ __forceinline__ float b2f(u16 u) {
    unsigned int x = ((unsigned int)u) << 16;
    float f;
    __builtin_memcpy(&f, &x, 4);
    return f;
}
__device__ __forceinline__ u16 f2b(float f) {
    unsigned int x;
    __builtin_memcpy(&x, &f, 4);
    unsigned int lsb = (x >> 16) & 1u;
    x += 0x7fffu + lsb;            // round-to-nearest-even (finite values)
    return (u16)(x >> 16);
}
__device__ __forceinline__ void store1(float* p, float v) { *p = v; }
__device__ __forceinline__ void store1(u16* p, float v)   { *p = f2b(v); }

// ---------------------------------------------------------------------------
// fp32 -> bf16 conversion (vectorized, memory-bound)
// ---------------------------------------------------------------------------
__global__ __launch_bounds__(256) void cvt_f32_bf16_kernel(
    const float* __restrict__ src, u16* __restrict__ dst, int n4)
{
    const int idx = blockIdx.x * 256 + threadIdx.x;
    if (idx >= n4) return;
    float4 v = reinterpret_cast<const float4*>(src)[idx];
    ushort4 o;
    o.x = f2b(v.x); o.y = f2b(v.y); o.z = f2b(v.z); o.w = f2b(v.w);
    reinterpret_cast<ushort4*>(dst)[idx] = o;
}

// ---------------------------------------------------------------------------
// MFMA GEMM (m97 pattern): out[m,n] = A[m,:].W[n,:] (+bias), K=512, N=512.
// XCD-chunked remap: the 4 n-blocks of one m-tile run adjacently on one XCD
// (A panel L2-hot; all 4 B panels = 512KB L2-resident).  [T1, m192]
// TRB variant additionally emits out^T (vt[b][ch][tok]) via an LDS bounce --
// replaces the standalone transpose_v kernel.
// ---------------------------------------------------------------------------
template <typename OT, bool BIAS, bool TRB>
__global__ __launch_bounds__(256) void mfma_gemm_kernel(
    const u16* __restrict__ A, const u16* __restrict__ W,
    const float* __restrict__ bias, OT* __restrict__ out,
    u16* __restrict__ vt_out)
{
    __shared__ u16 SH[TRB ? 128 * TRP : 16384];   // Asm/Bsm (+bounce if TRB)
    u16* Asm = SH;
    u16* Bsm = SH + 8192;

    const int tid  = threadIdx.x;
    const int lane = tid & 63;
    const int w    = tid >> 6;          // wave 0..3

    // bijective XCD-chunked remap (nwg % 8 == 0 for all grids used here)
    const int nwg = gridDim.x * gridDim.y;
    const int lid = blockIdx.y * gridDim.x + blockIdx.x;
    int wid = lid;
    if ((nwg & 7) == 0) {
        const int chunk = nwg >> 3;
        wid = (lid & 7) * chunk + (lid >> 3);
    }
    const int m0 = (wid >> 2) * 128;    // n-minor: same-m blocks adjacent
    const int n0 = (wid & 3) * 128;

    const int wm   = (w & 1) * 64;      // wave row offset in tile
    const int wn   = (w >> 1) * 64;     // wave col offset in tile

    const int srow = lane >> 3;         // staging row within 8-row chunk
    const int scol = (lane & 7) * 8;    // staging k-offset (elems)

    f32x4 acc[4][4] = {};

    for (int kt = 0; kt < 8; ++kt) {
        const int k0 = kt * 64;
        __syncthreads();                 // LDS free (prev iter's reads done)
        #pragma unroll
        for (int i = 0; i < 4; ++i) {
            const int rb = w * 8 + i * 32;
            __builtin_amdgcn_global_load_lds(
                (const __attribute__((address_space(1))) void*)
                    (A + (size_t)(m0 + rb + srow) * 512 + k0 + scol),
                (__attribute__((address_space(3))) void*)(Asm + rb * 64),
                16, 0, 0);
        }
        #pragma unroll
        for (int i = 0; i < 4; ++i) {
            const int rb = w * 8 + i * 32;
            __builtin_amdgcn_global_load_lds(
                (const __attribute__((address_space(1))) void*)
                    (W + (size_t)(n0 + rb + srow) * 512 + k0 + scol),
                (__attribute__((address_space(3))) void*)(Bsm + rb * 64),
                16, 0, 0);
        }
        __syncthreads();                 // staging complete

        #pragma unroll
        for (int kh = 0; kh < 2; ++kh) {
            bf16x8 af[4], bfr[4];
            #pragma unroll
            for (int t = 0; t < 4; ++t)
                af[t] = *reinterpret_cast<const bf16x8*>(
                    &Asm[(wm + t * 16 + (lane & 15)) * 64 + kh * 32 + (lane >> 4) * 8]);
            #pragma unroll
            for (int t = 0; t < 4; ++t)
                bfr[t] = *reinterpret_cast<const bf16x8*>(
                    &Bsm[(wn + t * 16 + (lane & 15)) * 64 + kh * 32 + (lane >> 4) * 8]);
            #pragma unroll
            for (int i = 0; i < 4; ++i)
                #pragma unroll
                for (int j = 0; j < 4; ++j)
                    acc[i][j] = __builtin_amdgcn_mfma_f32_16x16x32_bf16(
                        af[i], bfr[j], acc[i][j], 0, 0, 0);
        }
    }

    // epilogue: C/D layout col=lane&15, row=(lane>>4)*4+reg  [m89/m91]
    const int quad = lane >> 4;
    const int col  = lane & 15;
    #pragma unroll
    for (int j = 0; j < 4; ++j) {
        const int n = n0 + wn + j * 16 + col;
        const float bv = BIAS ? bias[n] : 0.f;
        #pragma unroll
        for (int i = 0; i < 4; ++i) {
            #pragma unroll
            for (int r = 0; r < 4; ++r) {
                const int m = m0 + wm + i * 16 + quad * 4 + r;
                store1(&out[(size_t)m * 512 + n], acc[i][j][r] + bv);
            }
        }
    }

    if constexpr (TRB) {
        // ---- transposed output: vt[b][channel][token] via LDS bounce
        __syncthreads();                 // all K-loop LDS reads done
        #pragma unroll
        for (int j = 0; j < 4; ++j) {
            const int nl = wn + j * 16 + col;
            #pragma unroll
            for (int i = 0; i < 4; ++i)
                #pragma unroll
                for (int r = 0; r < 4; ++r) {
                    const int ml = wm + i * 16 + quad * 4 + r;
                    SH[nl * TRP + ml] = f2b(acc[i][j][r]);
                }
        }
        __syncthreads();
        // coalesced row stores: thread = (n_row = tid>>1, m_half = (tid&1)*64)
        const int nr = tid >> 1, mh = (tid & 1) * 64;
        const int ng = n0 + nr;
        #pragma unroll
        for (int kc = 0; kc < 8; ++kc) {
            const int ml  = mh + kc * 8;
            const int gm  = m0 + ml;
            const int bb  = gm / NTOK;          // 8-token chunks never cross
            const int tok = gm - bb * NTOK;     // (NTOK % 8 == 0)
            u16x8 val = *reinterpret_cast<const u16x8*>(&SH[nr * TRP + ml]);
            *reinterpret_cast<u16x8*>(
                &vt_out[((size_t)bb * CHN + ng) * NTOK + tok]) = val;
        }
    }
}

// ---------------------------------------------------------------------------
// Adaptive avg-pool x (b,56,56,c) fp32 -> x_pool (b,144,c) bf16.
// ---------------------------------------------------------------------------
__global__ __launch_bounds__(256) void pool_x_kernel(
    const float* __restrict__ x, u16* __restrict__ x_pool)
{
    const int b = blockIdx.x, pq = blockIdx.y;
    const int p = pq / PS, qq = pq % PS;
    const int sp_ = (p * HHW) / PS, ep_ = ((p + 1) * HHW + PS - 1) / PS;
    const int sq_ = (qq * HHW) / PS, eq_ = ((qq + 1) * HHW + PS - 1) / PS;
    const float inv = 1.0f / (float)((ep_ - sp_) * (eq_ - sq_));
    for (int ch = threadIdx.x; ch < CHN; ch += 256) {
        float acc = 0.f;
        for (int y = sp_; y < ep_; ++y)
            for (int xx = sq_; xx < eq_; ++xx)
                acc += x[((size_t)b * NTOK + y * HHW + xx) * CHN + ch];
        x_pool[((size_t)b * NAG + pq) * CHN + ch] = f2b(acc * inv);
    }
}

// ---------------------------------------------------------------------------
// Stage-1 flash attention, MFMA version (unchanged).
// ---------------------------------------------------------------------------
__global__ __launch_bounds__(64) void stage1_mfma_kernel(
    const u16* __restrict__ k, const u16* __restrict__ vt,
    const u16* __restrict__ agent, u16* __restrict__ avt)
{
    __shared__ u16 Pl[16 * S1PP];

    const int lb   = blockIdx.x;
    const int work = (lb & 7) * 144 + (lb >> 3);  // bijective XCD swizzle (1152%8==0)
    const int at   = work % 9;                    // agent tile 0..8
    const int r2   = work / 9;
    const int h    = r2 & 7;
    const int b    = r2 >> 3;

    const int lane = threadIdx.x;
    const int c = lane & 15, g = lane >> 4;

    const u16* kp = k  + (size_t)b * NTOK * CHN + h * HD;
    const u16* vp = vt + ((size_t)(b * NH + h)) * HD * NTOK;
    const u16* ap = agent + ((size_t)b * NAG + at * 16 + c) * CHN + h * HD + g * 8;

    // A (agent) fragments resident in registers: rows=agents, k=d
    bf16x8 af0 = *reinterpret_cast<const bf16x8*>(ap);
    bf16x8 af1 = *reinterpret_cast<const bf16x8*>(ap + 32);

    f32x4 accO[4] = {};                 // O^T, d-tiles 0..3
    float m_ = -1e30f, l_ = 0.f;

    // prologue: K fragments for tile 0 (rows=keys, k=d)
    bf16x8 kf[8];
    #pragma unroll
    for (int kt = 0; kt < 4; ++kt)
        #pragma unroll
        for (int ks = 0; ks < 2; ++ks)
            kf[kt * 2 + ks] = *reinterpret_cast<const bf16x8*>(
                kp + (size_t)(kt * 16 + c) * CHN + ks * 32 + g * 8);

    for (int key0 = 0; key0 < NTOK; key0 += 64) {
        // issue current-tile Vt frags (rows=d, k=keys) + next-tile K frags
        bf16x8 vf[8];
        #pragma unroll
        for (int dt = 0; dt < 4; ++dt)
            #pragma unroll
            for (int kk = 0; kk < 2; ++kk)
                vf[dt * 2 + kk] = *reinterpret_cast<const bf16x8*>(
                    vp + (size_t)(dt * 16 + c) * NTOK + key0 + kk * 32 + g * 8);
        bf16x8 kn[8];
        const bool more = (key0 + 64) < NTOK;
        if (more) {
            #pragma unroll
            for (int kt = 0; kt < 4; ++kt)
                #pragma unroll
                for (int ks = 0; ks < 2; ++ks)
                    kn[kt * 2 + ks] = *reinterpret_cast<const bf16x8*>(
                        kp + (size_t)(key0 + 64 + kt * 16 + c) * CHN + ks * 32 + g * 8);
        }

        // S^T tiles: D[key][agent]
        f32x4 s[4] = {};
        #pragma unroll
        for (int kt = 0; kt < 4; ++kt) {
            s[kt] = __builtin_amdgcn_mfma_f32_16x16x32_bf16(kf[kt * 2 + 0], af0, s[kt], 0, 0, 0);
            s[kt] = __builtin_amdgcn_mfma_f32_16x16x32_bf16(kf[kt * 2 + 1], af1, s[kt], 0, 0, 0);
        }

        // online softmax: keys are in-lane (16 vals) + across g groups (xor 16,32)
        float tmax = -1e30f;
        #pragma unroll
        for (int kt = 0; kt < 4; ++kt)
            #pragma unroll
            for (int r = 0; r < 4; ++r) tmax = fmaxf(tmax, s[kt][r]);
        tmax = fmaxf(tmax, __shfl_xor(tmax, 16));
        tmax = fmaxf(tmax, __shfl_xor(tmax, 32));

        const float mnew  = fmaxf(m_, tmax * 0.125f);   // scale=1/8 folded here
        const float alpha = __expf(m_ - mnew);
        float psum = 0.f;
        #pragma unroll
        for (int kt = 0; kt < 4; ++kt) {
            float p0 = __expf(s[kt][0] * 0.125f - mnew);
            float p1 = __expf(s[kt][1] * 0.125f - mnew);
            float p2 = __expf(s[kt][2] * 0.125f - mnew);
            float p3 = __expf(s[kt][3] * 0.125f - mnew);
            psum += (p0 + p1) + (p2 + p3);
            ushort4 pk;
            pk.x = f2b(p0); pk.y = f2b(p1); pk.z = f2b(p2); pk.w = f2b(p3);
            // P[agent=c][key=kt*16+g*4 .. +3]
            *reinterpret_cast<ushort4*>(&Pl[c * S1PP + kt * 16 + g * 4]) = pk;
        }
        psum += __shfl_xor(psum, 16);
        psum += __shfl_xor(psum, 32);
        l_ = l_ * alpha + psum;
        m_ = mnew;
        #pragma unroll
        for (int dt = 0; dt < 4; ++dt) {
            accO[dt][0] *= alpha; accO[dt][1] *= alpha;
            accO[dt][2] *= alpha; accO[dt][3] *= alpha;
        }

        // cross-lane LDS write->read within the wave: force ordering
        asm volatile("s_waitcnt lgkmcnt(0)" ::: "memory");
        __builtin_amdgcn_sched_barrier(0);

        bf16x8 pf0 = *reinterpret_cast<const bf16x8*>(&Pl[c * S1PP + g * 8]);
        bf16x8 pf1 = *reinterpret_cast<const bf16x8*>(&Pl[c * S1PP + 32 + g * 8]);

        #pragma unroll
        for (int dt = 0; dt < 4; ++dt) {
            accO[dt] = __builtin_amdgcn_mfma_f32_16x16x32_bf16(vf[dt * 2 + 0], pf0, accO[dt], 0, 0, 0);
            accO[dt] = __builtin_amdgcn_mfma_f32_16x16x32_bf16(vf[dt * 2 + 1], pf1, accO[dt], 0, 0, 0);
        }

        if (more) {
            #pragma unroll
            for (int i = 0; i < 8; ++i) kf[i] = kn[i];
        }
    }

    // epilogue: lane holds O^T[d=dt*16+g*4+r][agent=at*16+c] -> write avt
    const float invl = 1.f / l_;
    const size_t dbase = (size_t)(b * NH + h) * HD;
    #pragma unroll
    for (int dt = 0; dt < 4; ++dt)
        #pragma unroll
        for (int r = 0; r < 4; ++r)
            avt[(dbase + dt * 16 + g * 4 + r) * NAG + at * 16 + c] =
                f2b(accO[dt][r] * invl);
}

// ---------------------------------------------------------------------------
// Stage-2 attention, MFMA + LDS-staged operands + fused depthwise conv.
// (round-13 passing version, unchanged: Pl aliases As, 42.75KB LDS,
//  3 blocks/CU)
// ---------------------------------------------------------------------------
__global__ __launch_bounds__(256, 3) void stage2_mfma_kernel(
    const u16* __restrict__ q,
    const u16* __restrict__ agent,
    const u16* __restrict__ avt,
    const u16* __restrict__ v,
    const float* __restrict__ dwc_w,
    const float* __restrict__ dwc_b,
    u16* __restrict__ xattn)
{
    // As (144x72 = 20736 B, dead after QK^T) overlaps Pl (4x16x152 = 19456 B)
    __shared__ __align__(16) u16 AsPl[NAG * ASP];
    __shared__ __align__(16) u16 AVs[HD * AVP];       // avt [64][144] p=152
    __shared__ float dwW[HD * 9];
    __shared__ float dwB[HD];

    const int h   = blockIdx.y;
    const int b   = blockIdx.z;
    const int tid = threadIdx.x;
    const int w    = tid >> 6;
    const int lane = tid & 63;
    const int c = lane & 15, g = lane >> 4;
    const int q0 = (blockIdx.x * 4 + w) * 16;     // 0..3120
    const int qg = q0 + c;
    const int y = qg / HHW, xx = qg % HHW;

    // Q fragment loads issued first (latency hides under staging)
    const u16* qp = q + ((size_t)b * NTOK + qg) * CHN + h * HD + g * 8;
    bf16x8 qf0 = *reinterpret_cast<const bf16x8*>(qp);
    bf16x8 qf1 = *reinterpret_cast<const bf16x8*>(qp + 32);

    // ---- cooperative staging: agent + avt + dw weights
    {
        const u16* ab = agent + (size_t)b * NAG * CHN + h * HD;
        for (int idx = tid; idx < NAG * 4; idx += 256) {       // 576 chunks
            const int r = idx >> 2, cc = (idx & 3) * 16;
            *reinterpret_cast<u16x8*>(&AsPl[r * ASP + cc]) =
                *reinterpret_cast<const u16x8*>(ab + (size_t)r * CHN + cc);
            *reinterpret_cast<u16x8*>(&AsPl[r * ASP + cc + 8]) =
                *reinterpret_cast<const u16x8*>(ab + (size_t)r * CHN + cc + 8);
        }
        const u16* avb = avt + (size_t)(b * NH + h) * HD * NAG;
        for (int idx = tid; idx < HD * 18; idx += 256) {       // 1152 chunks
            const int r = idx / 18, cc = (idx % 18) * 8;
            *reinterpret_cast<u16x8*>(&AVs[r * AVP + cc]) =
                *reinterpret_cast<const u16x8*>(avb + (size_t)r * NAG + cc);
        }
        for (int idx = tid; idx < HD * 9; idx += 256)
            dwW[idx] = dwc_w[(h * HD + idx / 9) * 9 + (idx % 9)];
        if (tid < HD) dwB[tid] = dwc_b[h * HD + tid];
    }
    __syncthreads();

    // ---- depthwise conv: 36 independent clamped loads, consumed on arrival
    float conv[4][4];
    #pragma unroll
    for (int dt = 0; dt < 4; ++dt)
        #pragma unroll
        for (int r = 0; r < 4; ++r) conv[dt][r] = 0.f;
    {
        const u16* vq = v + ((size_t)b * NTOK + qg) * CHN + h * HD + g * 4;
        #pragma unroll
        for (int dy = -1; dy <= 1; ++dy) {
            #pragma unroll
            for (int dx = -1; dx <= 1; ++dx) {
                const int tap = (dy + 1) * 3 + (dx + 1);
                const int yy = y + dy, xc = xx + dx;
                const bool ok = (yy >= 0 && yy < HHW && xc >= 0 && xc < HHW);
                const u16* vr = vq + (ok ? (ptrdiff_t)(dy * HHW + dx) * CHN : 0);
                ushort4 vv0 = *reinterpret_cast<const ushort4*>(vr);
                ushort4 vv1 = *reinterpret_cast<const ushort4*>(vr + 16);
                ushort4 vv2 = *reinterpret_cast<const ushort4*>(vr + 32);
                ushort4 vv3 = *reinterpret_cast<const ushort4*>(vr + 48);
                if (ok) {
                    const float* wt = &dwW[(g * 4) * 9 + tap];
                    conv[0][0] += b2f(vv0.x) * wt[(0 * 16 + 0) * 9];
                    conv[0][1] += b2f(vv0.y) * wt[(0 * 16 + 1) * 9];
                    conv[0][2] += b2f(vv0.z) * wt[(0 * 16 + 2) * 9];
                    conv[0][3] += b2f(vv0.w) * wt[(0 * 16 + 3) * 9];
                    conv[1][0] += b2f(vv1.x) * wt[(1 * 16 + 0) * 9];
                    conv[1][1] += b2f(vv1.y) * wt[(1 * 16 + 1) * 9];
                    conv[1][2] += b2f(vv1.z) * wt[(1 * 16 + 2) * 9];
                    conv[1][3] += b2f(vv1.w) * wt[(1 * 16 + 3) * 9];
                    conv[2][0] += b2f(vv2.x) * wt[(2 * 16 + 0) * 9];
                    conv[2][1] += b2f(vv2.y) * wt[(2 * 16 + 1) * 9];
                    conv[2][2] += b2f(vv2.z) * wt[(2 * 16 + 2) * 9];
                    conv[2][3] += b2f(vv2.w) * wt[(2 * 16 + 3) * 9];
                    conv[3][0] += b2f(vv3.x) * wt[(3 * 16 + 0) * 9];
                    conv[3][1] += b2f(vv3.y) * wt[(3 * 16 + 1) * 9];
                    conv[3][2] += b2f(vv3.z) * wt[(3 * 16 + 2) * 9];
                    conv[3][3] += b2f(vv3.w) * wt[(3 * 16 + 3) * 9];
                }
            }
        }
    }

    // ---- QK^T: S^T[agent][query], 9 agent tiles (A-frags from LDS)
    f32x4 s[9] = {};
    #pragma unroll
    for (int t = 0; t < 9; ++t) {
        bf16x8 af0 = *reinterpret_cast<const bf16x8*>(&AsPl[(t * 16 + c) * ASP + g * 8]);
        bf16x8 af1 = *reinterpret_cast<const bf16x8*>(&AsPl[(t * 16 + c) * ASP + 32 + g * 8]);
        s[t] = __builtin_amdgcn_mfma_f32_16x16x32_bf16(af0, qf0, s[t], 0, 0, 0);
        s[t] = __builtin_amdgcn_mfma_f32_16x16x32_bf16(af1, qf1, s[t], 0, 0, 0);
    }

    // barrier #2: all waves done reading As before Pl overwrites it (WAR)
    __syncthreads();

    // ---- softmax over agents: 36 in-lane + cross-g (xor 16,32)
    float mx = -1e30f;
    #pragma unroll
    for (int t = 0; t < 9; ++t)
        #pragma unroll
        for (int r = 0; r < 4; ++r) mx = fmaxf(mx, s[t][r]);
    mx = fmaxf(mx, __shfl_xor(mx, 16));
    mx = fmaxf(mx, __shfl_xor(mx, 32));
    mx *= 0.125f;

    u16* Pw = &AsPl[w * 16 * S2PP];     // Pl aliases As (dead)
    float ls = 0.f;
    #pragma unroll
    for (int t = 0; t < 9; ++t) {
        float p0 = __expf(s[t][0] * 0.125f - mx);
        float p1 = __expf(s[t][1] * 0.125f - mx);
        float p2 = __expf(s[t][2] * 0.125f - mx);
        float p3 = __expf(s[t][3] * 0.125f - mx);
        ls += (p0 + p1) + (p2 + p3);
        ushort4 pk;
        pk.x = f2b(p0); pk.y = f2b(p1); pk.z = f2b(p2); pk.w = f2b(p3);
        // P[query=c][agent=t*16+g*4 .. +3]
        *reinterpret_cast<ushort4*>(&Pw[c * S2PP + t * 16 + g * 4]) = pk;
    }
    ls += __shfl_xor(ls, 16);
    ls += __shfl_xor(ls, 32);
    const float inv = 1.f / ls;

    // same-wave LDS write->read ordering for the P tile
    asm volatile("s_waitcnt lgkmcnt(0)" ::: "memory");
    __builtin_amdgcn_sched_barrier(0);

    // ---- PV: O^T[d][query], AV-frags from LDS; 5th slice half-masked
    f32x4 o[4] = {};
    #pragma unroll
    for (int sl = 0; sl < 4; ++sl) {
        bf16x8 pf = *reinterpret_cast<const bf16x8*>(&Pw[c * S2PP + sl * 32 + g * 8]);
        #pragma unroll
        for (int dt = 0; dt < 4; ++dt) {
            bf16x8 avf = *reinterpret_cast<const bf16x8*>(
                &AVs[(dt * 16 + c) * AVP + sl * 32 + g * 8]);
            o[dt] = __builtin_amdgcn_mfma_f32_16x16x32_bf16(avf, pf, o[dt], 0, 0, 0);
        }
    }
    {   // slice 4: agents 128..143 live in lanes g<2; g>=2 contribute zeros
        bf16x8 pf = {};
        bf16x8 avf[4] = {{0,0,0,0,0,0,0,0},{0,0,0,0,0,0,0,0},
                         {0,0,0,0,0,0,0,0},{0,0,0,0,0,0,0,0}};
        if (g < 2) {
            pf = *reinterpret_cast<const bf16x8*>(&Pw[c * S2PP + 128 + g * 8]);
            #pragma unroll
            for (int dt = 0; dt < 4; ++dt)
                avf[dt] = *reinterpret_cast<const bf16x8*>(
                    &AVs[(dt * 16 + c) * AVP + 128 + g * 8]);
        }
        #pragma unroll
        for (int dt = 0; dt < 4; ++dt)
            o[dt] = __builtin_amdgcn_mfma_f32_16x16x32_bf16(avf[dt], pf, o[dt], 0, 0, 0);
    }

    // ---- epilogue: O^T[d=dt*16+g*4+r][query=qg]; + conv + bias + store
    u16* outp = xattn + ((size_t)b * NTOK + qg) * CHN + h * HD + g * 4;
    #pragma unroll
    for (int dt = 0; dt < 4; ++dt) {
        ushort4 o4;
        o4.x = f2b(o[dt][0] * inv + dwB[dt * 16 + g * 4 + 0] + conv[dt][0]);
        o4.y = f2b(o[dt][1] * inv + dwB[dt * 16 + g * 4 + 1] + conv[dt][1]);
        o4.z = f2b(o[dt][2] * inv + dwB[dt * 16 + g * 4 + 2] + conv[dt][2]);
        o4.w = f2b(o[dt][3] * inv + dwB[dt * 16 + g * 4 + 3] + conv[dt][3]);
        *reinterpret_cast<ushort4*>(outp + dt * 16) = o4;
    }
}

// ---------------------------------------------------------------------------
extern "C" void kernel_launch(void* const* d_in, const int* in_sizes, int n_in,
                              void* d_out, int out_size, void* d_ws, size_t ws_size,
                              hipStream_t stream)
{
    const float* x      = (const float*)d_in[0];
    const float* qkv_w  = (const float*)d_in[1];
    const float* proj_w = (const float*)d_in[2];
    const float* proj_b = (const float*)d_in[3];
    const float* dwc_w  = (const float*)d_in[4];
    const float* dwc_b  = (const float*)d_in[5];
    float* out = (float*)d_out;

    const size_t nqkv = (size_t)BATCH * NTOK * CHN;       // 25,690,112
    // Buffer choreography (all race-free by stream order):
    //   d_out.lo: xb (bf16 x) until q-GEMM; then dead; final proj writes fp32
    //             over full d_out.
    //   d_out.hi: Vt (v transposed, written by v-GEMM), then q after stage-1.
    //   x.lo:     k (bf16), then attn (k dead after stage-1)
    //   x.hi:     v (bf16)
    u16* xb  = (u16*)d_out;           // bf16 x
    u16* vt  = xb + nqkv;             // Vt [b][512][3136] (d_out.hi)
    u16* qb  = xb + nqkv;             // q, same region, after stage-1
    u16* kb  = (u16*)d_in[0];         // k  (x buffer lower half)
    u16* vb  = kb + nqkv;             // v  (x buffer upper half)
    u16* attn = kb;                   // attn overwrites k (dead after stage1)

    // ws: x_pool/agent/avt (3 x 2,359,296 B) + wb (2,097,152 B) = 9.18 MB
    char* p = (char*)d_ws;
    u16* x_pool  = (u16*)p;  p += (size_t)BATCH * NAG * CHN * 2;
    u16* agent   = (u16*)p;  p += (size_t)BATCH * NAG * CHN * 2;
    u16* avt     = (u16*)p;  p += (size_t)BATCH * NH * HD * NAG * 2;
    u16* wb      = (u16*)p;           // qkv_w (786432) + proj_w (262144) bf16
    u16* Wq_b = wb;
    u16* Wk_b = wb + (size_t)262144;
    u16* Wv_b = wb + (size_t)524288;
    u16* Wp_b = wb + (size_t)786432;

    // 1. pool x (fp32, exact) -> x_pool bf16      [reads x]
    pool_x_kernel<<<dim3(BATCH, NAG), 256, 0, stream>>>(x, x_pool);
    // 2. convert x -> xb (d_out.lo)               [reads x]
    cvt_f32_bf16_kernel<<<(int)(nqkv / 4 + 255) / 256, 256, 0, stream>>>(x, xb, (int)(nqkv / 4));
    // 3. convert weights -> wb
    cvt_f32_bf16_kernel<<<(786432 / 4 + 255) / 256, 256, 0, stream>>>(qkv_w, wb, 786432 / 4);
    cvt_f32_bf16_kernel<<<(262144 / 4 + 255) / 256, 256, 0, stream>>>(proj_w, Wp_b, 262144 / 4);
    // 4. agent = x_pool @ Wq^T  (M = 2304)
    mfma_gemm_kernel<u16, false, false><<<dim3(18, 4), 256, 0, stream>>>(
        x_pool, Wq_b, nullptr, agent, nullptr);
    // 5. k = xb @ Wk^T -> x.lo  (x fp32 fully consumed by 1&2)
    mfma_gemm_kernel<u16, false, false><<<dim3(392, 4), 256, 0, stream>>>(
        xb, Wk_b, nullptr, kb, nullptr);
    // 6. v = xb @ Wv^T -> x.hi  AND  vt = v^T -> d_out.hi (fused transpose)
    mfma_gemm_kernel<u16, false, true><<<dim3(392, 4), 256, 0, stream>>>(
        xb, Wv_b, nullptr, vb, vt);
    // 7. stage-1 flash attention (MFMA) -> avt [b][h][d][144]
    stage1_mfma_kernel<<<dim3(1152), 64, 0, stream>>>(kb, vt, agent, avt);
    // 8. q = xb @ Wq^T -> d_out.hi (Vt dead; xb dead afterwards)
    mfma_gemm_kernel<u16, false, false><<<dim3(392, 4), 256, 0, stream>>>(
        xb, Wq_b, nullptr, qb, nullptr);
    // 9. stage-2 MFMA + dw conv -> attn (x.lo; k dead, disjoint from q/v)
    stage2_mfma_kernel<<<dim3(49, NH, BATCH), 256, 0, stream>>>(
        qb, agent, avt, vb, dwc_w, dwc_b, attn);
    // 10. out = attn @ proj_w^T + proj_b -> full d_out fp32 (xb,q dead)
    mfma_gemm_kernel<float, true, false><<<dim3(392, 4), 256, 0, stream>>>(
        attn, Wp_b, proj_b, out, nullptr);
}

// Round 17
// 707.689 us; speedup vs baseline: 1.0662x; 1.0053x over previous
//
#include <hip/hip_runtime.h>
#include <hip/hip_bf16.h>
#include <math.h>

typedef unsigned short u16;
typedef __attribute__((ext_vector_type(8))) unsigned short u16x8;
typedef __attribute__((ext_vector_type(8))) short bf16x8;
typedef __attribute__((ext_vector_type(4))) float f32x4;

#define BATCH 16
#define NTOK  3136
#define CHN   512
#define NH    8
#define HD    64
#define HHW   56
#define NAG   144
#define PS    12

#define S1PP   72      // stage-1 P-tile pitch (u16)
#define S2PP   152     // stage-2 P-tile pitch (u16)
#define ASP    72      // stage-2 agent LDS pitch
#define AVP    152     // stage-2 avt LDS pitch
#define TRP    136     // v-GEMM transpose bounce pitch (u16), mult of 8

__device__ __forceinline__ float b2f(u16 u) {
    unsigned int x = ((unsigned int)u) << 16;
    float f;
    __builtin_memcpy(&f, &x, 4);
    return f;
}
__device__ __forceinline__ u16 f2b(float f) {
    unsigned int x;
    __builtin_memcpy(&x, &f, 4);
    unsigned int lsb = (x >> 16) & 1u;
    x += 0x7fffu + lsb;            // round-to-nearest-even (finite values)
    return (u16)(x >> 16);
}
__device__ __forceinline__ void store1(float* p, float v) { *p = v; }
__device__ __forceinline__ void store1(u16* p, float v)   { *p = f2b(v); }

// ---------------------------------------------------------------------------
// fp32 -> bf16 conversion (vectorized, memory-bound)
// ---------------------------------------------------------------------------
__global__ __launch_bounds__(256) void cvt_f32_bf16_kernel(
    const float* __restrict__ src, u16* __restrict__ dst, int n4)
{
    const int idx = blockIdx.x * 256 + threadIdx.x;
    if (idx >= n4) return;
    float4 v = reinterpret_cast<const float4*>(src)[idx];
    ushort4 o;
    o.x = f2b(v.x); o.y = f2b(v.y); o.z = f2b(v.z); o.w = f2b(v.w);
    reinterpret_cast<ushort4*>(dst)[idx] = o;
}

// ---------------------------------------------------------------------------
// MFMA GEMM (m97 pattern): out[m,n] = A[m,:].W[n,:] (+bias), K=512, N=512.
// XCD-chunked remap; TRB variant also emits out^T via an LDS bounce.
// ---------------------------------------------------------------------------
template <typename OT, bool BIAS, bool TRB>
__global__ __launch_bounds__(256) void mfma_gemm_kernel(
    const u16* __restrict__ A, const u16* __restrict__ W,
    const float* __restrict__ bias, OT* __restrict__ out,
    u16* __restrict__ vt_out)
{
    __shared__ u16 SH[TRB ? 128 * TRP : 16384];   // Asm/Bsm (+bounce if TRB)
    u16* Asm = SH;
    u16* Bsm = SH + 8192;

    const int tid  = threadIdx.x;
    const int lane = tid & 63;
    const int w    = tid >> 6;          // wave 0..3

    // bijective XCD-chunked remap (nwg % 8 == 0 for all grids used here)
    const int nwg = gridDim.x * gridDim.y;
    const int lid = blockIdx.y * gridDim.x + blockIdx.x;
    int wid = lid;
    if ((nwg & 7) == 0) {
        const int chunk = nwg >> 3;
        wid = (lid & 7) * chunk + (lid >> 3);
    }
    const int m0 = (wid >> 2) * 128;    // n-minor: same-m blocks adjacent
    const int n0 = (wid & 3) * 128;

    const int wm   = (w & 1) * 64;      // wave row offset in tile
    const int wn   = (w >> 1) * 64;     // wave col offset in tile

    const int srow = lane >> 3;         // staging row within 8-row chunk
    const int scol = (lane & 7) * 8;    // staging k-offset (elems)

    f32x4 acc[4][4] = {};

    for (int kt = 0; kt < 8; ++kt) {
        const int k0 = kt * 64;
        __syncthreads();                 // LDS free (prev iter's reads done)
        #pragma unroll
        for (int i = 0; i < 4; ++i) {
            const int rb = w * 8 + i * 32;
            __builtin_amdgcn_global_load_lds(
                (const __attribute__((address_space(1))) void*)
                    (A + (size_t)(m0 + rb + srow) * 512 + k0 + scol),
                (__attribute__((address_space(3))) void*)(Asm + rb * 64),
                16, 0, 0);
        }
        #pragma unroll
        for (int i = 0; i < 4; ++i) {
            const int rb = w * 8 + i * 32;
            __builtin_amdgcn_global_load_lds(
                (const __attribute__((address_space(1))) void*)
                    (W + (size_t)(n0 + rb + srow) * 512 + k0 + scol),
                (__attribute__((address_space(3))) void*)(Bsm + rb * 64),
                16, 0, 0);
        }
        __syncthreads();                 // staging complete

        #pragma unroll
        for (int kh = 0; kh < 2; ++kh) {
            bf16x8 af[4], bfr[4];
            #pragma unroll
            for (int t = 0; t < 4; ++t)
                af[t] = *reinterpret_cast<const bf16x8*>(
                    &Asm[(wm + t * 16 + (lane & 15)) * 64 + kh * 32 + (lane >> 4) * 8]);
            #pragma unroll
            for (int t = 0; t < 4; ++t)
                bfr[t] = *reinterpret_cast<const bf16x8*>(
                    &Bsm[(wn + t * 16 + (lane & 15)) * 64 + kh * 32 + (lane >> 4) * 8]);
            #pragma unroll
            for (int i = 0; i < 4; ++i)
                #pragma unroll
                for (int j = 0; j < 4; ++j)
                    acc[i][j] = __builtin_amdgcn_mfma_f32_16x16x32_bf16(
                        af[i], bfr[j], acc[i][j], 0, 0, 0);
        }
    }

    // epilogue: C/D layout col=lane&15, row=(lane>>4)*4+reg  [m89/m91]
    const int quad = lane >> 4;
    const int col  = lane & 15;
    #pragma unroll
    for (int j = 0; j < 4; ++j) {
        const int n = n0 + wn + j * 16 + col;
        const float bv = BIAS ? bias[n] : 0.f;
        #pragma unroll
        for (int i = 0; i < 4; ++i) {
            #pragma unroll
            for (int r = 0; r < 4; ++r) {
                const int m = m0 + wm + i * 16 + quad * 4 + r;
                store1(&out[(size_t)m * 512 + n], acc[i][j][r] + bv);
            }
        }
    }

    if constexpr (TRB) {
        // ---- transposed output: vt[b][channel][token] via LDS bounce
        __syncthreads();                 // all K-loop LDS reads done
        #pragma unroll
        for (int j = 0; j < 4; ++j) {
            const int nl = wn + j * 16 + col;
            #pragma unroll
            for (int i = 0; i < 4; ++i)
                #pragma unroll
                for (int r = 0; r < 4; ++r) {
                    const int ml = wm + i * 16 + quad * 4 + r;
                    SH[nl * TRP + ml] = f2b(acc[i][j][r]);
                }
        }
        __syncthreads();
        // coalesced row stores: thread = (n_row = tid>>1, m_half = (tid&1)*64)
        const int nr = tid >> 1, mh = (tid & 1) * 64;
        const int ng = n0 + nr;
        #pragma unroll
        for (int kc = 0; kc < 8; ++kc) {
            const int ml  = mh + kc * 8;
            const int gm  = m0 + ml;
            const int bb  = gm / NTOK;          // 8-token chunks never cross
            const int tok = gm - bb * NTOK;     // (NTOK % 8 == 0)
            u16x8 val = *reinterpret_cast<const u16x8*>(&SH[nr * TRP + ml]);
            *reinterpret_cast<u16x8*>(
                &vt_out[((size_t)bb * CHN + ng) * NTOK + tok]) = val;
        }
    }
}

// ---------------------------------------------------------------------------
// Adaptive avg-pool x (b,56,56,c) fp32 -> x_pool (b,144,c) bf16.
// ---------------------------------------------------------------------------
__global__ __launch_bounds__(256) void pool_x_kernel(
    const float* __restrict__ x, u16* __restrict__ x_pool)
{
    const int b = blockIdx.x, pq = blockIdx.y;
    const int p = pq / PS, qq = pq % PS;
    const int sp_ = (p * HHW) / PS, ep_ = ((p + 1) * HHW + PS - 1) / PS;
    const int sq_ = (qq * HHW) / PS, eq_ = ((qq + 1) * HHW + PS - 1) / PS;
    const float inv = 1.0f / (float)((ep_ - sp_) * (eq_ - sq_));
    for (int ch = threadIdx.x; ch < CHN; ch += 256) {
        float acc = 0.f;
        for (int y = sp_; y < ep_; ++y)
            for (int xx = sq_; xx < eq_; ++xx)
                acc += x[((size_t)b * NTOK + y * HHW + xx) * CHN + ch];
        x_pool[((size_t)b * NAG + pq) * CHN + ch] = f2b(acc * inv);
    }
}

// ---------------------------------------------------------------------------
// Stage-1 flash attention, MFMA, 4-wave key-split.
// 256 thr/block; wave w handles 13/12/12/12 of the 49 key tiles with its own
// (m,l,O) flash state and private P-tile; wave 0 merges the 4 partials in
// LDS (standard flash merge) and writes avt.  1152 blocks -> 18 waves/CU
// (was 4.5 with 1-wave blocks).
// ---------------------------------------------------------------------------
__global__ __launch_bounds__(256) void stage1_mfma_kernel(
    const u16* __restrict__ k, const u16* __restrict__ vt,
    const u16* __restrict__ agent, u16* __restrict__ avt)
{
    __shared__ u16   Pl[4][16 * S1PP];      // per-wave P tiles (9216 B)
    __shared__ float Mg[4][16], Lg[4][16];  // per-wave m,l per agent col
    __shared__ float Og[4][64][17];         // per-wave O frags (pad 17)

    const int lb   = blockIdx.x;
    const int work = (lb & 7) * 144 + (lb >> 3);  // bijective XCD swizzle (1152%8==0)
    const int at   = work % 9;                    // agent tile 0..8
    const int r2   = work / 9;
    const int h    = r2 & 7;
    const int b    = r2 >> 3;

    const int tid  = threadIdx.x;
    const int w    = tid >> 6;
    const int lane = tid & 63;
    const int c = lane & 15, g = lane >> 4;

    // key-tile range for this wave: 49 tiles -> 13,12,12,12
    const int tstart = (w == 0) ? 0 : (13 + (w - 1) * 12);
    const int tend   = tstart + ((w == 0) ? 13 : 12);

    const u16* kp = k  + (size_t)b * NTOK * CHN + h * HD;
    const u16* vp = vt + ((size_t)(b * NH + h)) * HD * NTOK;
    const u16* ap = agent + ((size_t)b * NAG + at * 16 + c) * CHN + h * HD + g * 8;

    // A (agent) fragments resident in registers: rows=agents, k=d
    bf16x8 af0 = *reinterpret_cast<const bf16x8*>(ap);
    bf16x8 af1 = *reinterpret_cast<const bf16x8*>(ap + 32);

    f32x4 accO[4] = {};                 // O^T, d-tiles 0..3
    float m_ = -1e30f, l_ = 0.f;

    u16* Plw = Pl[w];

    // prologue: K fragments for this wave's first tile (rows=keys, k=d)
    bf16x8 kf[8];
    #pragma unroll
    for (int kt = 0; kt < 4; ++kt)
        #pragma unroll
        for (int ks = 0; ks < 2; ++ks)
            kf[kt * 2 + ks] = *reinterpret_cast<const bf16x8*>(
                kp + (size_t)(tstart * 64 + kt * 16 + c) * CHN + ks * 32 + g * 8);

    for (int t = tstart; t < tend; ++t) {
        const int key0 = t * 64;
        // issue current-tile Vt frags (rows=d, k=keys) + next-tile K frags
        bf16x8 vf[8];
        #pragma unroll
        for (int dt = 0; dt < 4; ++dt)
            #pragma unroll
            for (int kk = 0; kk < 2; ++kk)
                vf[dt * 2 + kk] = *reinterpret_cast<const bf16x8*>(
                    vp + (size_t)(dt * 16 + c) * NTOK + key0 + kk * 32 + g * 8);
        bf16x8 kn[8];
        const bool more = (t + 1) < tend;
        if (more) {
            #pragma unroll
            for (int kt = 0; kt < 4; ++kt)
                #pragma unroll
                for (int ks = 0; ks < 2; ++ks)
                    kn[kt * 2 + ks] = *reinterpret_cast<const bf16x8*>(
                        kp + (size_t)(key0 + 64 + kt * 16 + c) * CHN + ks * 32 + g * 8);
        }

        // S^T tiles: D[key][agent]
        f32x4 s[4] = {};
        #pragma unroll
        for (int kt = 0; kt < 4; ++kt) {
            s[kt] = __builtin_amdgcn_mfma_f32_16x16x32_bf16(kf[kt * 2 + 0], af0, s[kt], 0, 0, 0);
            s[kt] = __builtin_amdgcn_mfma_f32_16x16x32_bf16(kf[kt * 2 + 1], af1, s[kt], 0, 0, 0);
        }

        // online softmax: keys in-lane (16 vals) + across g groups (xor 16,32)
        float tmax = -1e30f;
        #pragma unroll
        for (int kt = 0; kt < 4; ++kt)
            #pragma unroll
            for (int r = 0; r < 4; ++r) tmax = fmaxf(tmax, s[kt][r]);
        tmax = fmaxf(tmax, __shfl_xor(tmax, 16));
        tmax = fmaxf(tmax, __shfl_xor(tmax, 32));

        const float mnew  = fmaxf(m_, tmax * 0.125f);   // scale=1/8 folded here
        const float alpha = __expf(m_ - mnew);
        float psum = 0.f;
        #pragma unroll
        for (int kt = 0; kt < 4; ++kt) {
            float p0 = __expf(s[kt][0] * 0.125f - mnew);
            float p1 = __expf(s[kt][1] * 0.125f - mnew);
            float p2 = __expf(s[kt][2] * 0.125f - mnew);
            float p3 = __expf(s[kt][3] * 0.125f - mnew);
            psum += (p0 + p1) + (p2 + p3);
            ushort4 pk;
            pk.x = f2b(p0); pk.y = f2b(p1); pk.z = f2b(p2); pk.w = f2b(p3);
            // P[agent=c][key=kt*16+g*4 .. +3]
            *reinterpret_cast<ushort4*>(&Plw[c * S1PP + kt * 16 + g * 4]) = pk;
        }
        psum += __shfl_xor(psum, 16);
        psum += __shfl_xor(psum, 32);
        l_ = l_ * alpha + psum;
        m_ = mnew;
        #pragma unroll
        for (int dt = 0; dt < 4; ++dt) {
            accO[dt][0] *= alpha; accO[dt][1] *= alpha;
            accO[dt][2] *= alpha; accO[dt][3] *= alpha;
        }

        // cross-lane LDS write->read within the wave: force ordering
        asm volatile("s_waitcnt lgkmcnt(0)" ::: "memory");
        __builtin_amdgcn_sched_barrier(0);

        bf16x8 pf0 = *reinterpret_cast<const bf16x8*>(&Plw[c * S1PP + g * 8]);
        bf16x8 pf1 = *reinterpret_cast<const bf16x8*>(&Plw[c * S1PP + 32 + g * 8]);

        #pragma unroll
        for (int dt = 0; dt < 4; ++dt) {
            accO[dt] = __builtin_amdgcn_mfma_f32_16x16x32_bf16(vf[dt * 2 + 0], pf0, accO[dt], 0, 0, 0);
            accO[dt] = __builtin_amdgcn_mfma_f32_16x16x32_bf16(vf[dt * 2 + 1], pf1, accO[dt], 0, 0, 0);
        }

        if (more) {
            #pragma unroll
            for (int i = 0; i < 8; ++i) kf[i] = kn[i];
        }
    }

    // ---- publish partials (m_, l_ uniform across g for fixed c)
    if (g == 0) { Mg[w][c] = m_; Lg[w][c] = l_; }
    #pragma unroll
    for (int dt = 0; dt < 4; ++dt)
        #pragma unroll
        for (int r = 0; r < 4; ++r)
            Og[w][lane][dt * 4 + r] = accO[dt][r];
    __syncthreads();

    // ---- wave 0 merges the 4 partial flash states and writes avt
    if (w == 0) {
        const float m0_ = Mg[0][c], m1_ = Mg[1][c], m2_ = Mg[2][c], m3_ = Mg[3][c];
        const float ms  = fmaxf(fmaxf(m0_, m1_), fmaxf(m2_, m3_));
        const float s0 = __expf(m0_ - ms), s1 = __expf(m1_ - ms),
                    s2 = __expf(m2_ - ms), s3 = __expf(m3_ - ms);
        const float ls = Lg[0][c] * s0 + Lg[1][c] * s1 +
                         Lg[2][c] * s2 + Lg[3][c] * s3;
        const float invl = 1.f / ls;
        const size_t dbase = (size_t)(b * NH + h) * HD;
        #pragma unroll
        for (int dt = 0; dt < 4; ++dt)
            #pragma unroll
            for (int r = 0; r < 4; ++r) {
                const int i = dt * 4 + r;
                const float val = Og[0][lane][i] * s0 + Og[1][lane][i] * s1 +
                                  Og[2][lane][i] * s2 + Og[3][lane][i] * s3;
                avt[(dbase + dt * 16 + g * 4 + r) * NAG + at * 16 + c] =
                    f2b(val * invl);
            }
    }
}

// ---------------------------------------------------------------------------
// Stage-2 attention, MFMA + LDS-staged operands + fused depthwise conv.
// (round-13 passing version, unchanged: Pl aliases As, 42.75KB LDS,
//  3 blocks/CU)
// ---------------------------------------------------------------------------
__global__ __launch_bounds__(256, 3) void stage2_mfma_kernel(
    const u16* __restrict__ q,
    const u16* __restrict__ agent,
    const u16* __restrict__ avt,
    const u16* __restrict__ v,
    const float* __restrict__ dwc_w,
    const float* __restrict__ dwc_b,
    u16* __restrict__ xattn)
{
    // As (144x72 = 20736 B, dead after QK^T) overlaps Pl (4x16x152 = 19456 B)
    __shared__ __align__(16) u16 AsPl[NAG * ASP];
    __shared__ __align__(16) u16 AVs[HD * AVP];       // avt [64][144] p=152
    __shared__ float dwW[HD * 9];
    __shared__ float dwB[HD];

    const int h   = blockIdx.y;
    const int b   = blockIdx.z;
    const int tid = threadIdx.x;
    const int w    = tid >> 6;
    const int lane = tid & 63;
    const int c = lane & 15, g = lane >> 4;
    const int q0 = (blockIdx.x * 4 + w) * 16;     // 0..3120
    const int qg = q0 + c;
    const int y = qg / HHW, xx = qg % HHW;

    // Q fragment loads issued first (latency hides under staging)
    const u16* qp = q + ((size_t)b * NTOK + qg) * CHN + h * HD + g * 8;
    bf16x8 qf0 = *reinterpret_cast<const bf16x8*>(qp);
    bf16x8 qf1 = *reinterpret_cast<const bf16x8*>(qp + 32);

    // ---- cooperative staging: agent + avt + dw weights
    {
        const u16* ab = agent + (size_t)b * NAG * CHN + h * HD;
        for (int idx = tid; idx < NAG * 4; idx += 256) {       // 576 chunks
            const int r = idx >> 2, cc = (idx & 3) * 16;
            *reinterpret_cast<u16x8*>(&AsPl[r * ASP + cc]) =
                *reinterpret_cast<const u16x8*>(ab + (size_t)r * CHN + cc);
            *reinterpret_cast<u16x8*>(&AsPl[r * ASP + cc + 8]) =
                *reinterpret_cast<const u16x8*>(ab + (size_t)r * CHN + cc + 8);
        }
        const u16* avb = avt + (size_t)(b * NH + h) * HD * NAG;
        for (int idx = tid; idx < HD * 18; idx += 256) {       // 1152 chunks
            const int r = idx / 18, cc = (idx % 18) * 8;
            *reinterpret_cast<u16x8*>(&AVs[r * AVP + cc]) =
                *reinterpret_cast<const u16x8*>(avb + (size_t)r * NAG + cc);
        }
        for (int idx = tid; idx < HD * 9; idx += 256)
            dwW[idx] = dwc_w[(h * HD + idx / 9) * 9 + (idx % 9)];
        if (tid < HD) dwB[tid] = dwc_b[h * HD + tid];
    }
    __syncthreads();

    // ---- depthwise conv: 36 independent clamped loads, consumed on arrival
    float conv[4][4];
    #pragma unroll
    for (int dt = 0; dt < 4; ++dt)
        #pragma unroll
        for (int r = 0; r < 4; ++r) conv[dt][r] = 0.f;
    {
        const u16* vq = v + ((size_t)b * NTOK + qg) * CHN + h * HD + g * 4;
        #pragma unroll
        for (int dy = -1; dy <= 1; ++dy) {
            #pragma unroll
            for (int dx = -1; dx <= 1; ++dx) {
                const int tap = (dy + 1) * 3 + (dx + 1);
                const int yy = y + dy, xc = xx + dx;
                const bool ok = (yy >= 0 && yy < HHW && xc >= 0 && xc < HHW);
                const u16* vr = vq + (ok ? (ptrdiff_t)(dy * HHW + dx) * CHN : 0);
                ushort4 vv0 = *reinterpret_cast<const ushort4*>(vr);
                ushort4 vv1 = *reinterpret_cast<const ushort4*>(vr + 16);
                ushort4 vv2 = *reinterpret_cast<const ushort4*>(vr + 32);
                ushort4 vv3 = *reinterpret_cast<const ushort4*>(vr + 48);
                if (ok) {
                    const float* wt = &dwW[(g * 4) * 9 + tap];
                    conv[0][0] += b2f(vv0.x) * wt[(0 * 16 + 0) * 9];
                    conv[0][1] += b2f(vv0.y) * wt[(0 * 16 + 1) * 9];
                    conv[0][2] += b2f(vv0.z) * wt[(0 * 16 + 2) * 9];
                    conv[0][3] += b2f(vv0.w) * wt[(0 * 16 + 3) * 9];
                    conv[1][0] += b2f(vv1.x) * wt[(1 * 16 + 0) * 9];
                    conv[1][1] += b2f(vv1.y) * wt[(1 * 16 + 1) * 9];
                    conv[1][2] += b2f(vv1.z) * wt[(1 * 16 + 2) * 9];
                    conv[1][3] += b2f(vv1.w) * wt[(1 * 16 + 3) * 9];
                    conv[2][0] += b2f(vv2.x) * wt[(2 * 16 + 0) * 9];
                    conv[2][1] += b2f(vv2.y) * wt[(2 * 16 + 1) * 9];
                    conv[2][2] += b2f(vv2.z) * wt[(2 * 16 + 2) * 9];
                    conv[2][3] += b2f(vv2.w) * wt[(2 * 16 + 3) * 9];
                    conv[3][0] += b2f(vv3.x) * wt[(3 * 16 + 0) * 9];
                    conv[3][1] += b2f(vv3.y) * wt[(3 * 16 + 1) * 9];
                    conv[3][2] += b2f(vv3.z) * wt[(3 * 16 + 2) * 9];
                    conv[3][3] += b2f(vv3.w) * wt[(3 * 16 + 3) * 9];
                }
            }
        }
    }

    // ---- QK^T: S^T[agent][query], 9 agent tiles (A-frags from LDS)
    f32x4 s[9] = {};
    #pragma unroll
    for (int t = 0; t < 9; ++t) {
        bf16x8 af0 = *reinterpret_cast<const bf16x8*>(&AsPl[(t * 16 + c) * ASP + g * 8]);
        bf16x8 af1 = *reinterpret_cast<const bf16x8*>(&AsPl[(t * 16 + c) * ASP + 32 + g * 8]);
        s[t] = __builtin_amdgcn_mfma_f32_16x16x32_bf16(af0, qf0, s[t], 0, 0, 0);
        s[t] = __builtin_amdgcn_mfma_f32_16x16x32_bf16(af1, qf1, s[t], 0, 0, 0);
    }

    // barrier #2: all waves done reading As before Pl overwrites it (WAR)
    __syncthreads();

    // ---- softmax over agents: 36 in-lane + cross-g (xor 16,32)
    float mx = -1e30f;
    #pragma unroll
    for (int t = 0; t < 9; ++t)
        #pragma unroll
        for (int r = 0; r < 4; ++r) mx = fmaxf(mx, s[t][r]);
    mx = fmaxf(mx, __shfl_xor(mx, 16));
    mx = fmaxf(mx, __shfl_xor(mx, 32));
    mx *= 0.125f;

    u16* Pw = &AsPl[w * 16 * S2PP];     // Pl aliases As (dead)
    float ls = 0.f;
    #pragma unroll
    for (int t = 0; t < 9; ++t) {
        float p0 = __expf(s[t][0] * 0.125f - mx);
        float p1 = __expf(s[t][1] * 0.125f - mx);
        float p2 = __expf(s[t][2] * 0.125f - mx);
        float p3 = __expf(s[t][3] * 0.125f - mx);
        ls += (p0 + p1) + (p2 + p3);
        ushort4 pk;
        pk.x = f2b(p0); pk.y = f2b(p1); pk.z = f2b(p2); pk.w = f2b(p3);
        // P[query=c][agent=t*16+g*4 .. +3]
        *reinterpret_cast<ushort4*>(&Pw[c * S2PP + t * 16 + g * 4]) = pk;
    }
    ls += __shfl_xor(ls, 16);
    ls += __shfl_xor(ls, 32);
    const float inv = 1.f / ls;

    // same-wave LDS write->read ordering for the P tile
    asm volatile("s_waitcnt lgkmcnt(0)" ::: "memory");
    __builtin_amdgcn_sched_barrier(0);

    // ---- PV: O^T[d][query], AV-frags from LDS; 5th slice half-masked
    f32x4 o[4] = {};
    #pragma unroll
    for (int sl = 0; sl < 4; ++sl) {
        bf16x8 pf = *reinterpret_cast<const bf16x8*>(&Pw[c * S2PP + sl * 32 + g * 8]);
        #pragma unroll
        for (int dt = 0; dt < 4; ++dt) {
            bf16x8 avf = *reinterpret_cast<const bf16x8*>(
                &AVs[(dt * 16 + c) * AVP + sl * 32 + g * 8]);
            o[dt] = __builtin_amdgcn_mfma_f32_16x16x32_bf16(avf, pf, o[dt], 0, 0, 0);
        }
    }
    {   // slice 4: agents 128..143 live in lanes g<2; g>=2 contribute zeros
        bf16x8 pf = {};
        bf16x8 avf[4] = {{0,0,0,0,0,0,0,0},{0,0,0,0,0,0,0,0},
                         {0,0,0,0,0,0,0,0},{0,0,0,0,0,0,0,0}};
        if (g < 2) {
            pf = *reinterpret_cast<const bf16x8*>(&Pw[c * S2PP + 128 + g * 8]);
            #pragma unroll
            for (int dt = 0; dt < 4; ++dt)
                avf[dt] = *reinterpret_cast<const bf16x8*>(
                    &AVs[(dt * 16 + c) * AVP + 128 + g * 8]);
        }
        #pragma unroll
        for (int dt = 0; dt < 4; ++dt)
            o[dt] = __builtin_amdgcn_mfma_f32_16x16x32_bf16(avf[dt], pf, o[dt], 0, 0, 0);
    }

    // ---- epilogue: O^T[d=dt*16+g*4+r][query=qg]; + conv + bias + store
    u16* outp = xattn + ((size_t)b * NTOK + qg) * CHN + h * HD + g * 4;
    #pragma unroll
    for (int dt = 0; dt < 4; ++dt) {
        ushort4 o4;
        o4.x = f2b(o[dt][0] * inv + dwB[dt * 16 + g * 4 + 0] + conv[dt][0]);
        o4.y = f2b(o[dt][1] * inv + dwB[dt * 16 + g * 4 + 1] + conv[dt][1]);
        o4.z = f2b(o[dt][2] * inv + dwB[dt * 16 + g * 4 + 2] + conv[dt][2]);
        o4.w = f2b(o[dt][3] * inv + dwB[dt * 16 + g * 4 + 3] + conv[dt][3]);
        *reinterpret_cast<ushort4*>(outp + dt * 16) = o4;
    }
}

// ---------------------------------------------------------------------------
extern "C" void kernel_launch(void* const* d_in, const int* in_sizes, int n_in,
                              void* d_out, int out_size, void* d_ws, size_t ws_size,
                              hipStream_t stream)
{
    const float* x      = (const float*)d_in[0];
    const float* qkv_w  = (const float*)d_in[1];
    const float* proj_w = (const float*)d_in[2];
    const float* proj_b = (const float*)d_in[3];
    const float* dwc_w  = (const float*)d_in[4];
    const float* dwc_b  = (const float*)d_in[5];
    float* out = (float*)d_out;

    const size_t nqkv = (size_t)BATCH * NTOK * CHN;       // 25,690,112
    // Buffer choreography (all race-free by stream order):
    //   d_out.lo: xb (bf16 x) until q-GEMM; then dead; final proj writes fp32
    //             over full d_out.
    //   d_out.hi: Vt (v transposed, written by v-GEMM), then q after stage-1.
    //   x.lo:     k (bf16), then attn (k dead after stage-1)
    //   x.hi:     v (bf16)
    u16* xb  = (u16*)d_out;           // bf16 x
    u16* vt  = xb + nqkv;             // Vt [b][512][3136] (d_out.hi)
    u16* qb  = xb + nqkv;             // q, same region, after stage-1
    u16* kb  = (u16*)d_in[0];         // k  (x buffer lower half)
    u16* vb  = kb + nqkv;             // v  (x buffer upper half)
    u16* attn = kb;                   // attn overwrites k (dead after stage1)

    // ws: x_pool/agent/avt (3 x 2,359,296 B) + wb (2,097,152 B) = 9.18 MB
    char* p = (char*)d_ws;
    u16* x_pool  = (u16*)p;  p += (size_t)BATCH * NAG * CHN * 2;
    u16* agent   = (u16*)p;  p += (size_t)BATCH * NAG * CHN * 2;
    u16* avt     = (u16*)p;  p += (size_t)BATCH * NH * HD * NAG * 2;
    u16* wb      = (u16*)p;           // qkv_w (786432) + proj_w (262144) bf16
    u16* Wq_b = wb;
    u16* Wk_b = wb + (size_t)262144;
    u16* Wv_b = wb + (size_t)524288;
    u16* Wp_b = wb + (size_t)786432;

    // 1. pool x (fp32, exact) -> x_pool bf16      [reads x]
    pool_x_kernel<<<dim3(BATCH, NAG), 256, 0, stream>>>(x, x_pool);
    // 2. convert x -> xb (d_out.lo)               [reads x]
    cvt_f32_bf16_kernel<<<(int)(nqkv / 4 + 255) / 256, 256, 0, stream>>>(x, xb, (int)(nqkv / 4));
    // 3. convert weights -> wb
    cvt_f32_bf16_kernel<<<(786432 / 4 + 255) / 256, 256, 0, stream>>>(qkv_w, wb, 786432 / 4);
    cvt_f32_bf16_kernel<<<(262144 / 4 + 255) / 256, 256, 0, stream>>>(proj_w, Wp_b, 262144 / 4);
    // 4. agent = x_pool @ Wq^T  (M = 2304)
    mfma_gemm_kernel<u16, false, false><<<dim3(18, 4), 256, 0, stream>>>(
        x_pool, Wq_b, nullptr, agent, nullptr);
    // 5. k = xb @ Wk^T -> x.lo  (x fp32 fully consumed by 1&2)
    mfma_gemm_kernel<u16, false, false><<<dim3(392, 4), 256, 0, stream>>>(
        xb, Wk_b, nullptr, kb, nullptr);
    // 6. v = xb @ Wv^T -> x.hi  AND  vt = v^T -> d_out.hi (fused transpose)
    mfma_gemm_kernel<u16, false, true><<<dim3(392, 4), 256, 0, stream>>>(
        xb, Wv_b, nullptr, vb, vt);
    // 7. stage-1 flash attention (MFMA, 4-wave key-split) -> avt
    stage1_mfma_kernel<<<dim3(1152), 256, 0, stream>>>(kb, vt, agent, avt);
    // 8. q = xb @ Wq^T -> d_out.hi (Vt dead; xb dead afterwards)
    mfma_gemm_kernel<u16, false, false><<<dim3(392, 4), 256, 0, stream>>>(
        xb, Wq_b, nullptr, qb, nullptr);
    // 9. stage-2 MFMA + dw conv -> attn (x.lo; k dead, disjoint from q/v)
    stage2_mfma_kernel<<<dim3(49, NH, BATCH), 256, 0, stream>>>(
        qb, agent, avt, vb, dwc_w, dwc_b, attn);
    // 10. out = attn @ proj_w^T + proj_b -> full d_out fp32 (xb,q dead)
    mfma_gemm_kernel<float, true, false><<<dim3(392, 4), 256, 0, stream>>>(
        attn, Wp_b, proj_b, out, nullptr);
}